// Round 1
// baseline (5266.317 us; speedup 1.0000x reference)
//
#include <hip/hip_runtime.h>
#include <hip/hip_bf16.h>

// LightGCN: 3 rounds of SpMM (A_hat @ emb, A in COO), layer-mean, then
// sigmoid(U @ I^T) on 2048 gathered user/item rows.
//
// d_ws layout (floats):
//   embA [N_NODES*64] | embB [N_NODES*64] | acc [N_NODES*64] | U [B*64] | I [B*64]
// Total ~116 MB.

#define EMB 64

// Copy concat(user_emb, item_emb) into emb and acc (float4-vectorized).
__global__ void ALGN_init_emb(const float4* __restrict__ ue, const float4* __restrict__ ie,
                              float4* __restrict__ emb, float4* __restrict__ acc,
                              int nUser4, int n4) {
    int t = blockIdx.x * blockDim.x + threadIdx.x;
    if (t >= n4) return;
    float4 v = (t < nUser4) ? ue[t] : ie[t - nUser4];
    emb[t] = v;
    acc[t] = v;
}

// Edge-parallel scatter: 16 threads per edge, each handles 4 contiguous feats.
// next[row*64+f] += val * cur[col*64+f]
__global__ void ALGN_scatter_edges(const float4* __restrict__ cur, float* __restrict__ next,
                                   const float* __restrict__ vals,
                                   const int* __restrict__ rows,
                                   const int* __restrict__ cols, int nEdges) {
    long tid = (long)blockIdx.x * blockDim.x + threadIdx.x;
    int e = (int)(tid >> 4);
    if (e >= nEdges) return;
    int c = (int)(tid & 15);
    int col = cols[e];
    int row = rows[e];
    float v = vals[e];
    float4 x = cur[col * 16 + c];
    float* dst = next + row * EMB + c * 4;
    atomicAdd(dst + 0, v * x.x);
    atomicAdd(dst + 1, v * x.y);
    atomicAdd(dst + 2, v * x.z);
    atomicAdd(dst + 3, v * x.w);
}

// acc += next (float4-vectorized)
__global__ void ALGN_add_acc(float4* __restrict__ acc, const float4* __restrict__ nxt, int n4) {
    int t = blockIdx.x * blockDim.x + threadIdx.x;
    if (t >= n4) return;
    float4 a = acc[t];
    float4 b = nxt[t];
    a.x += b.x; a.y += b.y; a.z += b.z; a.w += b.w;
    acc[t] = a;
}

// Gather batch rows and fold in the /(L+1)=0.25 layer-mean scale (split as
// 0.25 per side would square it; put full 0.25 on each side -> dot scaled by
// 1/16 which equals (acc/4)u . (acc/4)i. Correct.)
__global__ void ALGN_gather_ui(const float* __restrict__ acc,
                               const int* __restrict__ users, const int* __restrict__ items,
                               float* __restrict__ U, float* __restrict__ I,
                               int batch, int nUser) {
    int t = blockIdx.x * blockDim.x + threadIdx.x;
    if (t >= batch * EMB) return;
    int b = t >> 6, c = t & 63;
    U[t] = acc[users[b] * EMB + c] * 0.25f;
    I[t] = acc[(nUser + items[b]) * EMB + c] * 0.25f;
}

// out[a][b] = sigmoid(dot(U[a], I[b])). 16x16 output tile per block.
__global__ void ALGN_gemm_sigmoid(const float* __restrict__ U, const float* __restrict__ I,
                                  float* __restrict__ out, int B) {
    __shared__ float su[16][EMB + 1];   // +1 pad: kills same-bank stride-64 conflicts
    __shared__ float si[16][EMB + 1];
    int tx = threadIdx.x;   // 0..15 -> item (col)
    int ty = threadIdx.y;   // 0..15 -> user (row)
    int row0 = blockIdx.y * 16;
    int col0 = blockIdx.x * 16;
    int tid = ty * 16 + tx;
    for (int k = tid; k < 16 * EMB; k += 256) {
        int r = k >> 6, c = k & 63;
        su[r][c] = U[(row0 + r) * EMB + c];
        si[r][c] = I[(col0 + r) * EMB + c];
    }
    __syncthreads();
    float s = 0.f;
#pragma unroll
    for (int k = 0; k < EMB; ++k) s += su[ty][k] * si[tx][k];
    out[(row0 + ty) * B + (col0 + tx)] = 1.f / (1.f + __expf(-s));
}

extern "C" void kernel_launch(void* const* d_in, const int* in_sizes, int n_in,
                              void* d_out, int out_size, void* d_ws, size_t ws_size,
                              hipStream_t stream) {
    const float* user_emb = (const float*)d_in[0];
    const float* item_emb = (const float*)d_in[1];
    const float* adj_vals = (const float*)d_in[2];
    const int*   adj_rows = (const int*)d_in[3];
    const int*   adj_cols = (const int*)d_in[4];
    const int*   users    = (const int*)d_in[5];
    const int*   items    = (const int*)d_in[6];
    float* out = (float*)d_out;

    const int nUserF = in_sizes[0];           // N_USER * 64
    const int nItemF = in_sizes[1];           // N_ITEM * 64
    const int nEdges = in_sizes[2];
    const int batch  = in_sizes[5];
    const int nUser  = nUserF / EMB;
    const int totalF = nUserF + nItemF;       // N_NODES * 64
    const int n4     = totalF / 4;

    float* embA = (float*)d_ws;
    float* embB = embA + totalF;
    float* acc  = embB + totalF;
    float* Ub   = acc  + totalF;
    float* Ib   = Ub   + batch * EMB;

    // init emb + acc
    ALGN_init_emb<<<(n4 + 255) / 256, 256, 0, stream>>>(
        (const float4*)user_emb, (const float4*)item_emb,
        (float4*)embA, (float4*)acc, nUserF / 4, n4);

    float* cur = embA;
    float* nxt = embB;
    const long scatterThreads = (long)nEdges * 16;
    const int  scatterBlocks  = (int)((scatterThreads + 255) / 256);

    for (int layer = 0; layer < 3; ++layer) {
        hipMemsetAsync(nxt, 0, (size_t)totalF * sizeof(float), stream);
        ALGN_scatter_edges<<<scatterBlocks, 256, 0, stream>>>(
            (const float4*)cur, nxt, adj_vals, adj_rows, adj_cols, nEdges);
        ALGN_add_acc<<<(n4 + 255) / 256, 256, 0, stream>>>(
            (float4*)acc, (const float4*)nxt, n4);
        float* tmp = cur; cur = nxt; nxt = tmp;
    }

    ALGN_gather_ui<<<(batch * EMB + 255) / 256, 256, 0, stream>>>(
        acc, users, items, Ub, Ib, batch, nUser);

    dim3 gg(batch / 16, batch / 16);
    dim3 gb(16, 16);
    ALGN_gemm_sigmoid<<<gg, gb, 0, stream>>>(Ub, Ib, out, batch);
}

// Round 2
// 747.182 us; speedup vs baseline: 7.0482x; 7.0482x over previous
//
#include <hip/hip_runtime.h>
#include <hip/hip_bf16.h>

// LightGCN on MI355X. R2: atomic-free SpMM via on-device CSR build.
//
// R1 post-mortem: edge-parallel f32 atomics wrote 2 GB/dispatch to HBM
// (vs 38 MB useful) at ~0.3 TB/s effective -> 1689 us x3. Fix: histogram +
// prefix-scan + stable fill to build CSR each call (graph-capture safe),
// then one-wave-per-row gather SpMM, single coalesced store per row.
//
// d_ws layout (4-byte elems):
//   embA [totalF] | embB [totalF] | Ub [B*64] | Ib [B*64] |
//   sortedVal [E] (f32) | sortedCol [E] (i32) | rowPtr [N+1] | rowOff [N]
// totalF = 150000*64 = 9.6M -> total ~95 MB (R1 used 116 MB, so it fits).

#define EMB 64
#define SCAN_BS 512

// ---------- init: concat(user_emb, item_emb) -> embA ----------
__global__ void ALGN_init_emb(const float4* __restrict__ ue, const float4* __restrict__ ie,
                              float4* __restrict__ emb, int nUser4, int n4) {
    int t = blockIdx.x * blockDim.x + threadIdx.x;
    if (t >= n4) return;
    emb[t] = (t < nUser4) ? ue[t] : ie[t - nUser4];
}

// ---------- CSR build ----------
// counts (in rowOff, pre-zeroed): per-row degree histogram
__global__ void ALGN_hist(const int* __restrict__ rows, int* __restrict__ cnt, int nE) {
    int e = blockIdx.x * blockDim.x + threadIdx.x;
    if (e < nE) atomicAdd(&cnt[rows[e]], 1);
}

// pass 1: per-block exclusive scan of cnt -> rowPtr, block sums -> bsums
__global__ void ALGN_scan1(const int* __restrict__ in, int* __restrict__ out,
                           int* __restrict__ bsums, int n) {
    __shared__ int tmp[SCAN_BS];
    int t = threadIdx.x;
    int g = blockIdx.x * SCAN_BS + t;
    int v = (g < n) ? in[g] : 0;
    tmp[t] = v;
    __syncthreads();
    for (int off = 1; off < SCAN_BS; off <<= 1) {
        int x = (t >= off) ? tmp[t - off] : 0;
        __syncthreads();
        tmp[t] += x;
        __syncthreads();
    }
    if (g < n) out[g] = tmp[t] - v;                 // exclusive
    if (t == SCAN_BS - 1) bsums[blockIdx.x] = tmp[t];
}

// pass 2: single-block exclusive scan of bsums (nb <= SCAN_BS; 293 here)
__global__ void ALGN_scan2(int* __restrict__ bsums, int nb) {
    __shared__ int tmp[SCAN_BS];
    int t = threadIdx.x;
    int v = (t < nb) ? bsums[t] : 0;
    tmp[t] = v;
    __syncthreads();
    for (int off = 1; off < SCAN_BS; off <<= 1) {
        int x = (t >= off) ? tmp[t - off] : 0;
        __syncthreads();
        tmp[t] += x;
        __syncthreads();
    }
    if (t < nb) bsums[t] = tmp[t] - v;
}

// pass 3: add block offsets; copy final ptr into rowOff (fill cursor);
// set rowPtr[n] = nE
__global__ void ALGN_scan3(int* __restrict__ rowPtr, int* __restrict__ rowOff,
                           const int* __restrict__ bsums, int n, int nE) {
    int g = blockIdx.x * SCAN_BS + threadIdx.x;
    if (g < n) {
        int v = rowPtr[g] + bsums[blockIdx.x];
        rowPtr[g] = v;
        rowOff[g] = v;
    }
    if (g == 0) rowPtr[n] = nE;
}

// fill: stable-ish scatter of edges into CSR order (order within a row is
// nondeterministic -- fine, f32 sum tolerance is loose)
__global__ void ALGN_fill(const int* __restrict__ rows, const int* __restrict__ cols,
                          const float* __restrict__ vals, int* __restrict__ rowOff,
                          int* __restrict__ sCol, float* __restrict__ sVal, int nE) {
    int e = blockIdx.x * blockDim.x + threadIdx.x;
    if (e >= nE) return;
    int pos = atomicAdd(&rowOff[rows[e]], 1);
    sCol[pos] = cols[e];
    sVal[pos] = vals[e];
}

// ---------- SpMM: one wave per row, lane = feature ----------
__global__ void ALGN_spmm_csr(const float* __restrict__ cur, float* __restrict__ next,
                              const int* __restrict__ rowPtr, const int* __restrict__ sCol,
                              const float* __restrict__ sVal, int nNodes) {
    int w = (int)((blockIdx.x * blockDim.x + threadIdx.x) >> 6);
    int lane = threadIdx.x & 63;
    if (w >= nNodes) return;                        // wave-uniform exit
    int beg = rowPtr[w];
    int end = rowPtr[w + 1];
    float s = 0.f;
    for (int base = beg; base < end; base += 64) {
        int m = end - base; if (m > 64) m = 64;
        int   c = 0;
        float v = 0.f;
        if (lane < m) { c = sCol[base + lane]; v = sVal[base + lane]; }
        for (int j = 0; j < m; ++j) {
            int   cj = __shfl(c, j);
            float vj = __shfl(v, j);
            s += vj * cur[cj * EMB + lane];         // 256 B coalesced per wave
        }
    }
    next[w * EMB + lane] = s;                       // single clean store
}

// ---------- batch gather-accumulate (layer mean folded: 0.25 per side) ----
__global__ void ALGN_gather_add(const float* __restrict__ emb,
                                const int* __restrict__ users, const int* __restrict__ items,
                                float* __restrict__ U, float* __restrict__ I,
                                int batch, int nUser) {
    int t = blockIdx.x * blockDim.x + threadIdx.x;
    if (t >= batch * EMB) return;
    int b = t >> 6, c = t & 63;
    U[t] += emb[users[b] * EMB + c] * 0.25f;
    I[t] += emb[(nUser + items[b]) * EMB + c] * 0.25f;
}

// ---------- sigmoid(U @ I^T), 16x16 tile per 256-thread block ----------
__global__ void ALGN_gemm_sigmoid(const float* __restrict__ U, const float* __restrict__ I,
                                  float* __restrict__ out, int B) {
    __shared__ float su[16][EMB + 1];
    __shared__ float si[16][EMB + 1];
    int tx = threadIdx.x, ty = threadIdx.y;
    int row0 = blockIdx.y * 16, col0 = blockIdx.x * 16;
    int tid = ty * 16 + tx;
    for (int k = tid; k < 16 * EMB; k += 256) {
        int r = k >> 6, c = k & 63;
        su[r][c] = U[(row0 + r) * EMB + c];
        si[r][c] = I[(col0 + r) * EMB + c];
    }
    __syncthreads();
    float s = 0.f;
#pragma unroll
    for (int k = 0; k < EMB; ++k) s += su[ty][k] * si[tx][k];
    out[(row0 + ty) * B + (col0 + tx)] = 1.f / (1.f + __expf(-s));
}

extern "C" void kernel_launch(void* const* d_in, const int* in_sizes, int n_in,
                              void* d_out, int out_size, void* d_ws, size_t ws_size,
                              hipStream_t stream) {
    const float* user_emb = (const float*)d_in[0];
    const float* item_emb = (const float*)d_in[1];
    const float* adj_vals = (const float*)d_in[2];
    const int*   adj_rows = (const int*)d_in[3];
    const int*   adj_cols = (const int*)d_in[4];
    const int*   users    = (const int*)d_in[5];
    const int*   items    = (const int*)d_in[6];
    float* out = (float*)d_out;

    const int nUserF = in_sizes[0];
    const int nItemF = in_sizes[1];
    const int nEdges = in_sizes[2];
    const int batch  = in_sizes[5];
    const int nUser  = nUserF / EMB;
    const int totalF = nUserF + nItemF;
    const int nNodes = totalF / EMB;
    const int n4     = totalF / 4;

    float* embA = (float*)d_ws;
    float* embB = embA + totalF;
    float* Ub   = embB + totalF;
    float* Ib   = Ub   + (size_t)batch * EMB;
    float* sVal = Ib   + (size_t)batch * EMB;
    int*   sCol = (int*)(sVal + nEdges);
    int*   rowPtr = sCol + nEdges;
    int*   rowOff = rowPtr + (nNodes + 1);
    // scan block sums tucked after rowOff
    int*   bsums  = rowOff + nNodes;

    const int nScanBlocks = (nNodes + SCAN_BS - 1) / SCAN_BS;   // 293 <= 512

    // zero: fill cursors + batch accumulators
    hipMemsetAsync(rowOff, 0, (size_t)nNodes * sizeof(int), stream);
    hipMemsetAsync(Ub, 0, (size_t)batch * EMB * sizeof(float) * 2, stream); // Ub+Ib contiguous

    ALGN_init_emb<<<(n4 + 255) / 256, 256, 0, stream>>>(
        (const float4*)user_emb, (const float4*)item_emb, (float4*)embA, nUserF / 4, n4);

    // ---- CSR build ----
    ALGN_hist<<<(nEdges + 255) / 256, 256, 0, stream>>>(adj_rows, rowOff, nEdges);
    ALGN_scan1<<<nScanBlocks, SCAN_BS, 0, stream>>>(rowOff, rowPtr, bsums, nNodes);
    ALGN_scan2<<<1, SCAN_BS, 0, stream>>>(bsums, nScanBlocks);
    ALGN_scan3<<<nScanBlocks, SCAN_BS, 0, stream>>>(rowPtr, rowOff, bsums, nNodes, nEdges);
    ALGN_fill<<<(nEdges + 255) / 256, 256, 0, stream>>>(
        adj_rows, adj_cols, adj_vals, rowOff, sCol, sVal, nEdges);

    // ---- layer 0 contribution ----
    ALGN_gather_add<<<(batch * EMB + 255) / 256, 256, 0, stream>>>(
        embA, users, items, Ub, Ib, batch, nUser);

    // ---- 3 propagation layers ----
    float* cur = embA;
    float* nxt = embB;
    const int spmmBlocks = (nNodes * 64 + 255) / 256;   // 4 waves/block, 1 row/wave
    for (int layer = 0; layer < 3; ++layer) {
        ALGN_spmm_csr<<<spmmBlocks, 256, 0, stream>>>(cur, nxt, rowPtr, sCol, sVal, nNodes);
        ALGN_gather_add<<<(batch * EMB + 255) / 256, 256, 0, stream>>>(
            nxt, users, items, Ub, Ib, batch, nUser);
        float* tmp = cur; cur = nxt; nxt = tmp;
    }

    dim3 gg(batch / 16, batch / 16);
    dim3 gb(16, 16);
    ALGN_gemm_sigmoid<<<gg, gb, 0, stream>>>(Ub, Ib, out, batch);
}

// Round 3
// 607.547 us; speedup vs baseline: 8.6682x; 1.2298x over previous
//
#include <hip/hip_runtime.h>
#include <hip/hip_bf16.h>

// LightGCN on MI355X. R3.
// R2 post-mortem: fill = 151 us with 192 MB WRITE (12x amplification from
// two separate 4 B random scatters/edge); spmm ~140 us each (1 vmem
// wave-instr per edge, 64 lanes x 1 feat).
// R3: (a) CSR payload = packed int2{col,val} -> one 8 B scatter/edge;
//     (b) spmm: 16 lanes/row x float4/lane, 4 rows/wave, unroll x4 ->
//         4 edges per wave-instr, 4 gathers in flight, no shfl.
//
// d_ws layout (4-byte elems):
//   embA [totalF] | embB [totalF] | Ub [B*64] | Ib [B*64] |
//   pairs [E int2] | rowPtr [N+1] | rowOff [N] | bsums [512]
// ~94 MB total (R2 used ~95 MB, fits).

#define EMB 64
#define SCAN_BS 512

__global__ void ALGN_init_emb(const float4* __restrict__ ue, const float4* __restrict__ ie,
                              float4* __restrict__ emb, int nUser4, int n4) {
    int t = blockIdx.x * blockDim.x + threadIdx.x;
    if (t >= n4) return;
    emb[t] = (t < nUser4) ? ue[t] : ie[t - nUser4];
}

// ---------- CSR build ----------
__global__ void ALGN_hist(const int* __restrict__ rows, int* __restrict__ cnt, int nE) {
    int e = blockIdx.x * blockDim.x + threadIdx.x;
    if (e < nE) atomicAdd(&cnt[rows[e]], 1);
}

__global__ void ALGN_scan1(const int* __restrict__ in, int* __restrict__ out,
                           int* __restrict__ bsums, int n) {
    __shared__ int tmp[SCAN_BS];
    int t = threadIdx.x;
    int g = blockIdx.x * SCAN_BS + t;
    int v = (g < n) ? in[g] : 0;
    tmp[t] = v;
    __syncthreads();
    for (int off = 1; off < SCAN_BS; off <<= 1) {
        int x = (t >= off) ? tmp[t - off] : 0;
        __syncthreads();
        tmp[t] += x;
        __syncthreads();
    }
    if (g < n) out[g] = tmp[t] - v;                 // exclusive
    if (t == SCAN_BS - 1) bsums[blockIdx.x] = tmp[t];
}

__global__ void ALGN_scan2(int* __restrict__ bsums, int nb) {
    __shared__ int tmp[SCAN_BS];
    int t = threadIdx.x;
    int v = (t < nb) ? bsums[t] : 0;
    tmp[t] = v;
    __syncthreads();
    for (int off = 1; off < SCAN_BS; off <<= 1) {
        int x = (t >= off) ? tmp[t - off] : 0;
        __syncthreads();
        tmp[t] += x;
        __syncthreads();
    }
    if (t < nb) bsums[t] = tmp[t] - v;
}

__global__ void ALGN_scan3(int* __restrict__ rowPtr, int* __restrict__ rowOff,
                           const int* __restrict__ bsums, int n, int nE) {
    int g = blockIdx.x * SCAN_BS + threadIdx.x;
    if (g < n) {
        int v = rowPtr[g] + bsums[blockIdx.x];
        rowPtr[g] = v;
        rowOff[g] = v;
    }
    if (g == 0) rowPtr[n] = nE;
}

// one 8 B store per edge (col + val bits interleaved)
__global__ void ALGN_fill(const int* __restrict__ rows, const int* __restrict__ cols,
                          const float* __restrict__ vals, int* __restrict__ rowOff,
                          int2* __restrict__ pairs, int nE) {
    int e = blockIdx.x * blockDim.x + threadIdx.x;
    if (e >= nE) return;
    int pos = atomicAdd(&rowOff[rows[e]], 1);
    int2 p;
    p.x = cols[e];
    p.y = __float_as_int(vals[e]);
    pairs[pos] = p;
}

// ---------- SpMM: 16 lanes per row, float4 per lane, 4 rows per wave ------
__global__ void ALGN_spmm_csr(const float4* __restrict__ cur4, float4* __restrict__ next4,
                              const int* __restrict__ rowPtr, const int2* __restrict__ pairs,
                              int nNodes) {
    int tid = blockIdx.x * blockDim.x + threadIdx.x;
    int row = tid >> 4;          // one row per 16-lane sub-group
    int fl  = tid & 15;          // float4 slot within the 64-float row
    if (row >= nNodes) return;
    int beg = rowPtr[row];
    int end = rowPtr[row + 1];
    float4 s = make_float4(0.f, 0.f, 0.f, 0.f);
    int j = beg;
    // 4 edges in flight: 4 independent 256 B gathers per sub-group
    for (; j + 4 <= end; j += 4) {
        int2 e0 = pairs[j + 0];
        int2 e1 = pairs[j + 1];
        int2 e2 = pairs[j + 2];
        int2 e3 = pairs[j + 3];
        float4 x0 = cur4[(size_t)e0.x * 16 + fl];
        float4 x1 = cur4[(size_t)e1.x * 16 + fl];
        float4 x2 = cur4[(size_t)e2.x * 16 + fl];
        float4 x3 = cur4[(size_t)e3.x * 16 + fl];
        float v0 = __int_as_float(e0.y);
        float v1 = __int_as_float(e1.y);
        float v2 = __int_as_float(e2.y);
        float v3 = __int_as_float(e3.y);
        s.x += v0 * x0.x; s.y += v0 * x0.y; s.z += v0 * x0.z; s.w += v0 * x0.w;
        s.x += v1 * x1.x; s.y += v1 * x1.y; s.z += v1 * x1.z; s.w += v1 * x1.w;
        s.x += v2 * x2.x; s.y += v2 * x2.y; s.z += v2 * x2.z; s.w += v2 * x2.w;
        s.x += v3 * x3.x; s.y += v3 * x3.y; s.z += v3 * x3.z; s.w += v3 * x3.w;
    }
    for (; j < end; ++j) {
        int2 e = pairs[j];
        float4 x = cur4[(size_t)e.x * 16 + fl];
        float v = __int_as_float(e.y);
        s.x += v * x.x; s.y += v * x.y; s.z += v * x.z; s.w += v * x.w;
    }
    next4[(size_t)row * 16 + fl] = s;
}

// ---------- batch gather-accumulate (layer mean folded: 0.25 per side) ----
__global__ void ALGN_gather_add(const float* __restrict__ emb,
                                const int* __restrict__ users, const int* __restrict__ items,
                                float* __restrict__ U, float* __restrict__ I,
                                int batch, int nUser) {
    int t = blockIdx.x * blockDim.x + threadIdx.x;
    if (t >= batch * EMB) return;
    int b = t >> 6, c = t & 63;
    U[t] += emb[users[b] * EMB + c] * 0.25f;
    I[t] += emb[(nUser + items[b]) * EMB + c] * 0.25f;
}

// ---------- sigmoid(U @ I^T), 16x16 tile per 256-thread block ----------
__global__ void ALGN_gemm_sigmoid(const float* __restrict__ U, const float* __restrict__ I,
                                  float* __restrict__ out, int B) {
    __shared__ float su[16][EMB + 1];
    __shared__ float si[16][EMB + 1];
    int tx = threadIdx.x, ty = threadIdx.y;
    int row0 = blockIdx.y * 16, col0 = blockIdx.x * 16;
    int tid = ty * 16 + tx;
    for (int k = tid; k < 16 * EMB; k += 256) {
        int r = k >> 6, c = k & 63;
        su[r][c] = U[(row0 + r) * EMB + c];
        si[r][c] = I[(col0 + r) * EMB + c];
    }
    __syncthreads();
    float s = 0.f;
#pragma unroll
    for (int k = 0; k < EMB; ++k) s += su[ty][k] * si[tx][k];
    out[(row0 + ty) * B + (col0 + tx)] = 1.f / (1.f + __expf(-s));
}

extern "C" void kernel_launch(void* const* d_in, const int* in_sizes, int n_in,
                              void* d_out, int out_size, void* d_ws, size_t ws_size,
                              hipStream_t stream) {
    const float* user_emb = (const float*)d_in[0];
    const float* item_emb = (const float*)d_in[1];
    const float* adj_vals = (const float*)d_in[2];
    const int*   adj_rows = (const int*)d_in[3];
    const int*   adj_cols = (const int*)d_in[4];
    const int*   users    = (const int*)d_in[5];
    const int*   items    = (const int*)d_in[6];
    float* out = (float*)d_out;

    const int nUserF = in_sizes[0];
    const int nItemF = in_sizes[1];
    const int nEdges = in_sizes[2];
    const int batch  = in_sizes[5];
    const int nUser  = nUserF / EMB;
    const int totalF = nUserF + nItemF;
    const int nNodes = totalF / EMB;
    const int n4     = totalF / 4;

    float* embA = (float*)d_ws;
    float* embB = embA + totalF;
    float* Ub   = embB + totalF;
    float* Ib   = Ub   + (size_t)batch * EMB;
    int2*  pairs = (int2*)(Ib + (size_t)batch * EMB);
    int*   rowPtr = (int*)(pairs + nEdges);
    int*   rowOff = rowPtr + (nNodes + 1);
    int*   bsums  = rowOff + nNodes;

    const int nScanBlocks = (nNodes + SCAN_BS - 1) / SCAN_BS;   // 293 <= 512

    hipMemsetAsync(rowOff, 0, (size_t)nNodes * sizeof(int), stream);
    hipMemsetAsync(Ub, 0, (size_t)batch * EMB * sizeof(float) * 2, stream); // Ub+Ib contiguous

    ALGN_init_emb<<<(n4 + 255) / 256, 256, 0, stream>>>(
        (const float4*)user_emb, (const float4*)item_emb, (float4*)embA, nUserF / 4, n4);

    // ---- CSR build ----
    ALGN_hist<<<(nEdges + 255) / 256, 256, 0, stream>>>(adj_rows, rowOff, nEdges);
    ALGN_scan1<<<nScanBlocks, SCAN_BS, 0, stream>>>(rowOff, rowPtr, bsums, nNodes);
    ALGN_scan2<<<1, SCAN_BS, 0, stream>>>(bsums, nScanBlocks);
    ALGN_scan3<<<nScanBlocks, SCAN_BS, 0, stream>>>(rowPtr, rowOff, bsums, nNodes, nEdges);
    ALGN_fill<<<(nEdges + 255) / 256, 256, 0, stream>>>(
        adj_rows, adj_cols, adj_vals, rowOff, pairs, nEdges);

    // ---- layer 0 contribution ----
    ALGN_gather_add<<<(batch * EMB + 255) / 256, 256, 0, stream>>>(
        embA, users, items, Ub, Ib, batch, nUser);

    // ---- 3 propagation layers ----
    float* cur = embA;
    float* nxt = embB;
    const int spmmBlocks = (nNodes * 16 + 255) / 256;   // 16 threads per row
    for (int layer = 0; layer < 3; ++layer) {
        ALGN_spmm_csr<<<spmmBlocks, 256, 0, stream>>>(
            (const float4*)cur, (float4*)nxt, rowPtr, pairs, nNodes);
        ALGN_gather_add<<<(batch * EMB + 255) / 256, 256, 0, stream>>>(
            nxt, users, items, Ub, Ib, batch, nUser);
        float* tmp = cur; cur = nxt; nxt = tmp;
    }

    dim3 gg(batch / 16, batch / 16);
    dim3 gb(16, 16);
    ALGN_gemm_sigmoid<<<gg, gb, 0, stream>>>(Ub, Ib, out, batch);
}

// Round 5
// 511.522 us; speedup vs baseline: 10.2954x; 1.1877x over previous
//
#include <hip/hip_runtime.h>
#include <hip/hip_bf16.h>

// LightGCN on MI355X. R5 = R4 resubmit (R4 bench died on container
// infrastructure, kernel never ran).
// R3 post-mortem: fill is transaction/latency-structural (time invariant to
// write bytes) -- deferred. SpMM aggregate ~350 us is the big cost:
// 512 MB/layer of 256 B row gathers served by L3 at ~4.3 TB/s effective.
// This round: store propagated embeddings as bf16 -> halves gather/store/init
// bytes. Compute stays f32 (bf16->f32 expand is exact; stores round RTNE).
// Error budget: ~0.1% rel storage err x3 layers -> +~0.005 absmax, under the
// 1.98e-2 threshold (current 0.0039).
//
// d_ws layout: embA bf16[totalF] | embB bf16[totalF] | Ub f32[B*64] |
//   Ib f32[B*64] | pairs int2[E] | rowPtr[N+1] | rowOff[N] | bsums[512]
// ~56 MB total.

#define EMB 64
#define SCAN_BS 512

__device__ __forceinline__ float bf2f(unsigned short u) {
    union { unsigned int i; float f; } v;
    v.i = ((unsigned int)u) << 16;
    return v.f;
}
__device__ __forceinline__ unsigned short f2bf(float f) {
    union { float f; unsigned int i; } v;
    v.f = f;
    unsigned int lsb = (v.i >> 16) & 1;
    v.i += 0x7fffu + lsb;          // round-to-nearest-even
    return (unsigned short)(v.i >> 16);
}

// ---------- init: concat(user_emb, item_emb) -> bf16 embA ----------
__global__ void ALGN_init_emb(const float4* __restrict__ ue, const float4* __restrict__ ie,
                              ushort4* __restrict__ emb, int nUser4, int n4) {
    int t = blockIdx.x * blockDim.x + threadIdx.x;
    if (t >= n4) return;
    float4 v = (t < nUser4) ? ue[t] : ie[t - nUser4];
    ushort4 o;
    o.x = f2bf(v.x); o.y = f2bf(v.y); o.z = f2bf(v.z); o.w = f2bf(v.w);
    emb[t] = o;
}

// ---------- CSR build ----------
__global__ void ALGN_hist(const int* __restrict__ rows, int* __restrict__ cnt, int nE) {
    int e = blockIdx.x * blockDim.x + threadIdx.x;
    if (e < nE) atomicAdd(&cnt[rows[e]], 1);
}

__global__ void ALGN_scan1(const int* __restrict__ in, int* __restrict__ out,
                           int* __restrict__ bsums, int n) {
    __shared__ int tmp[SCAN_BS];
    int t = threadIdx.x;
    int g = blockIdx.x * SCAN_BS + t;
    int v = (g < n) ? in[g] : 0;
    tmp[t] = v;
    __syncthreads();
    for (int off = 1; off < SCAN_BS; off <<= 1) {
        int x = (t >= off) ? tmp[t - off] : 0;
        __syncthreads();
        tmp[t] += x;
        __syncthreads();
    }
    if (g < n) out[g] = tmp[t] - v;                 // exclusive
    if (t == SCAN_BS - 1) bsums[blockIdx.x] = tmp[t];
}

__global__ void ALGN_scan2(int* __restrict__ bsums, int nb) {
    __shared__ int tmp[SCAN_BS];
    int t = threadIdx.x;
    int v = (t < nb) ? bsums[t] : 0;
    tmp[t] = v;
    __syncthreads();
    for (int off = 1; off < SCAN_BS; off <<= 1) {
        int x = (t >= off) ? tmp[t - off] : 0;
        __syncthreads();
        tmp[t] += x;
        __syncthreads();
    }
    if (t < nb) bsums[t] = tmp[t] - v;
}

__global__ void ALGN_scan3(int* __restrict__ rowPtr, int* __restrict__ rowOff,
                           const int* __restrict__ bsums, int n, int nE) {
    int g = blockIdx.x * SCAN_BS + threadIdx.x;
    if (g < n) {
        int v = rowPtr[g] + bsums[blockIdx.x];
        rowPtr[g] = v;
        rowOff[g] = v;
    }
    if (g == 0) rowPtr[n] = nE;
}

__global__ void ALGN_fill(const int* __restrict__ rows, const int* __restrict__ cols,
                          const float* __restrict__ vals, int* __restrict__ rowOff,
                          int2* __restrict__ pairs, int nE) {
    int e = blockIdx.x * blockDim.x + threadIdx.x;
    if (e >= nE) return;
    int pos = atomicAdd(&rowOff[rows[e]], 1);
    int2 p;
    p.x = cols[e];
    p.y = __float_as_int(vals[e]);
    pairs[pos] = p;
}

// ---------- SpMM: 16 lanes/row, 4 bf16 feats/lane, unroll x4 ----------
__global__ void ALGN_spmm_csr(const ushort4* __restrict__ cur, ushort4* __restrict__ next,
                              const int* __restrict__ rowPtr, const int2* __restrict__ pairs,
                              int nNodes) {
    int tid = blockIdx.x * blockDim.x + threadIdx.x;
    int row = tid >> 4;          // one row per 16-lane sub-group
    int fl  = tid & 15;          // ushort4 slot within the 64-feat row
    if (row >= nNodes) return;
    int beg = rowPtr[row];
    int end = rowPtr[row + 1];
    float4 s = make_float4(0.f, 0.f, 0.f, 0.f);
    int j = beg;
    for (; j + 4 <= end; j += 4) {
        int2 e0 = pairs[j + 0];
        int2 e1 = pairs[j + 1];
        int2 e2 = pairs[j + 2];
        int2 e3 = pairs[j + 3];
        ushort4 x0 = cur[(size_t)e0.x * 16 + fl];
        ushort4 x1 = cur[(size_t)e1.x * 16 + fl];
        ushort4 x2 = cur[(size_t)e2.x * 16 + fl];
        ushort4 x3 = cur[(size_t)e3.x * 16 + fl];
        float v0 = __int_as_float(e0.y);
        float v1 = __int_as_float(e1.y);
        float v2 = __int_as_float(e2.y);
        float v3 = __int_as_float(e3.y);
        s.x += v0 * bf2f(x0.x); s.y += v0 * bf2f(x0.y); s.z += v0 * bf2f(x0.z); s.w += v0 * bf2f(x0.w);
        s.x += v1 * bf2f(x1.x); s.y += v1 * bf2f(x1.y); s.z += v1 * bf2f(x1.z); s.w += v1 * bf2f(x1.w);
        s.x += v2 * bf2f(x2.x); s.y += v2 * bf2f(x2.y); s.z += v2 * bf2f(x2.z); s.w += v2 * bf2f(x2.w);
        s.x += v3 * bf2f(x3.x); s.y += v3 * bf2f(x3.y); s.z += v3 * bf2f(x3.z); s.w += v3 * bf2f(x3.w);
    }
    for (; j < end; ++j) {
        int2 e = pairs[j];
        ushort4 x = cur[(size_t)e.x * 16 + fl];
        float v = __int_as_float(e.y);
        s.x += v * bf2f(x.x); s.y += v * bf2f(x.y); s.z += v * bf2f(x.z); s.w += v * bf2f(x.w);
    }
    ushort4 o;
    o.x = f2bf(s.x); o.y = f2bf(s.y); o.z = f2bf(s.z); o.w = f2bf(s.w);
    next[(size_t)row * 16 + fl] = o;
}

// ---------- batch gather-accumulate (layer mean 0.25 folded per side) -----
__global__ void ALGN_gather_add(const unsigned short* __restrict__ emb,
                                const int* __restrict__ users, const int* __restrict__ items,
                                float* __restrict__ U, float* __restrict__ I,
                                int batch, int nUser) {
    int t = blockIdx.x * blockDim.x + threadIdx.x;
    if (t >= batch * EMB) return;
    int b = t >> 6, c = t & 63;
    U[t] += bf2f(emb[users[b] * EMB + c]) * 0.25f;
    I[t] += bf2f(emb[(nUser + items[b]) * EMB + c]) * 0.25f;
}

// ---------- sigmoid(U @ I^T), 16x16 tile per 256-thread block ----------
__global__ void ALGN_gemm_sigmoid(const float* __restrict__ U, const float* __restrict__ I,
                                  float* __restrict__ out, int B) {
    __shared__ float su[16][EMB + 1];
    __shared__ float si[16][EMB + 1];
    int tx = threadIdx.x, ty = threadIdx.y;
    int row0 = blockIdx.y * 16, col0 = blockIdx.x * 16;
    int tid = ty * 16 + tx;
    for (int k = tid; k < 16 * EMB; k += 256) {
        int r = k >> 6, c = k & 63;
        su[r][c] = U[(row0 + r) * EMB + c];
        si[r][c] = I[(col0 + r) * EMB + c];
    }
    __syncthreads();
    float s = 0.f;
#pragma unroll
    for (int k = 0; k < EMB; ++k) s += su[ty][k] * si[tx][k];
    out[(row0 + ty) * B + (col0 + tx)] = 1.f / (1.f + __expf(-s));
}

extern "C" void kernel_launch(void* const* d_in, const int* in_sizes, int n_in,
                              void* d_out, int out_size, void* d_ws, size_t ws_size,
                              hipStream_t stream) {
    const float* user_emb = (const float*)d_in[0];
    const float* item_emb = (const float*)d_in[1];
    const float* adj_vals = (const float*)d_in[2];
    const int*   adj_rows = (const int*)d_in[3];
    const int*   adj_cols = (const int*)d_in[4];
    const int*   users    = (const int*)d_in[5];
    const int*   items    = (const int*)d_in[6];
    float* out = (float*)d_out;

    const int nUserF = in_sizes[0];
    const int nItemF = in_sizes[1];
    const int nEdges = in_sizes[2];
    const int batch  = in_sizes[5];
    const int nUser  = nUserF / EMB;
    const int totalF = nUserF + nItemF;
    const int nNodes = totalF / EMB;
    const int n4     = totalF / 4;

    unsigned short* embA = (unsigned short*)d_ws;
    unsigned short* embB = embA + totalF;
    float* Ub = (float*)(embB + totalF);
    float* Ib = Ub + (size_t)batch * EMB;
    int2*  pairs = (int2*)(Ib + (size_t)batch * EMB);
    int*   rowPtr = (int*)(pairs + nEdges);
    int*   rowOff = rowPtr + (nNodes + 1);
    int*   bsums  = rowOff + nNodes;

    const int nScanBlocks = (nNodes + SCAN_BS - 1) / SCAN_BS;   // 293 <= 512

    hipMemsetAsync(rowOff, 0, (size_t)nNodes * sizeof(int), stream);
    hipMemsetAsync(Ub, 0, (size_t)batch * EMB * sizeof(float) * 2, stream); // Ub+Ib contiguous

    ALGN_init_emb<<<(n4 + 255) / 256, 256, 0, stream>>>(
        (const float4*)user_emb, (const float4*)item_emb, (ushort4*)embA, nUserF / 4, n4);

    // ---- CSR build ----
    ALGN_hist<<<(nEdges + 255) / 256, 256, 0, stream>>>(adj_rows, rowOff, nEdges);
    ALGN_scan1<<<nScanBlocks, SCAN_BS, 0, stream>>>(rowOff, rowPtr, bsums, nNodes);
    ALGN_scan2<<<1, SCAN_BS, 0, stream>>>(bsums, nScanBlocks);
    ALGN_scan3<<<nScanBlocks, SCAN_BS, 0, stream>>>(rowPtr, rowOff, bsums, nNodes, nEdges);
    ALGN_fill<<<(nEdges + 255) / 256, 256, 0, stream>>>(
        adj_rows, adj_cols, adj_vals, rowOff, pairs, nEdges);

    // ---- layer 0 contribution ----
    ALGN_gather_add<<<(batch * EMB + 255) / 256, 256, 0, stream>>>(
        embA, users, items, Ub, Ib, batch, nUser);

    // ---- 3 propagation layers ----
    unsigned short* cur = embA;
    unsigned short* nxt = embB;
    const int spmmBlocks = (nNodes * 16 + 255) / 256;   // 16 threads per row
    for (int layer = 0; layer < 3; ++layer) {
        ALGN_spmm_csr<<<spmmBlocks, 256, 0, stream>>>(
            (const ushort4*)cur, (ushort4*)nxt, rowPtr, pairs, nNodes);
        ALGN_gather_add<<<(batch * EMB + 255) / 256, 256, 0, stream>>>(
            nxt, users, items, Ub, Ib, batch, nUser);
        unsigned short* tmp = cur; cur = nxt; nxt = tmp;
    }

    dim3 gg(batch / 16, batch / 16);
    dim3 gb(16, 16);
    ALGN_gemm_sigmoid<<<gg, gb, 0, stream>>>(Ub, Ib, out, batch);
}

// Round 8
// 487.929 us; speedup vs baseline: 10.7932x; 1.0484x over previous
//
#include <hip/hip_runtime.h>
#include <hip/hip_bf16.h>

// LightGCN on MI355X. R8: deterministic backward-sliced propagation.
// R7 post-mortem: first launch correct (0.0078) but graph-replay output
// diverged (0.27) -- the only delta vs replay-proven R5 was the atomic-append
// list + device-count early-exit + duplicate-row concurrent writes. R8 keeps
// the slicing (6M -> 2.7M edge gathers) but replaces that machinery with
// idempotent flag arrays + flag-guarded full-grid SpMMs: no new atomics, no
// duplicate writers, no device-count-dependent control flow.
//
// d_ws layout: embA bf16[totalF] | embB bf16[totalF] | Ub f32[B*64] |
//   Ib f32[B*64] | pairs int2[E] | rowPtr[N+1] | rowOff[N] | bsums[512] |
//   flag2[N] | flagB[N]   (~58 MB)

#define EMB 64
#define SCAN_BS 512

__device__ __forceinline__ float bf2f(unsigned short u) {
    union { unsigned int i; float f; } v;
    v.i = ((unsigned int)u) << 16;
    return v.f;
}
__device__ __forceinline__ unsigned short f2bf(float f) {
    union { float f; unsigned int i; } v;
    v.f = f;
    unsigned int lsb = (v.i >> 16) & 1;
    v.i += 0x7fffu + lsb;          // round-to-nearest-even
    return (unsigned short)(v.i >> 16);
}

// ---------- init: concat(user_emb, item_emb) -> bf16 embA ----------
__global__ void ALGN_init_emb(const float4* __restrict__ ue, const float4* __restrict__ ie,
                              ushort4* __restrict__ emb, int nUser4, int n4) {
    int t = blockIdx.x * blockDim.x + threadIdx.x;
    if (t >= n4) return;
    float4 v = (t < nUser4) ? ue[t] : ie[t - nUser4];
    ushort4 o;
    o.x = f2bf(v.x); o.y = f2bf(v.y); o.z = f2bf(v.z); o.w = f2bf(v.w);
    emb[t] = o;
}

// ---------- CSR build ----------
__global__ void ALGN_hist(const int* __restrict__ rows, int* __restrict__ cnt, int nE) {
    int e = blockIdx.x * blockDim.x + threadIdx.x;
    if (e < nE) atomicAdd(&cnt[rows[e]], 1);
}

__global__ void ALGN_scan1(const int* __restrict__ in, int* __restrict__ out,
                           int* __restrict__ bsums, int n) {
    __shared__ int tmp[SCAN_BS];
    int t = threadIdx.x;
    int g = blockIdx.x * SCAN_BS + t;
    int v = (g < n) ? in[g] : 0;
    tmp[t] = v;
    __syncthreads();
    for (int off = 1; off < SCAN_BS; off <<= 1) {
        int x = (t >= off) ? tmp[t - off] : 0;
        __syncthreads();
        tmp[t] += x;
        __syncthreads();
    }
    if (g < n) out[g] = tmp[t] - v;                 // exclusive
    if (t == SCAN_BS - 1) bsums[blockIdx.x] = tmp[t];
}

__global__ void ALGN_scan2(int* __restrict__ bsums, int nb) {
    __shared__ int tmp[SCAN_BS];
    int t = threadIdx.x;
    int v = (t < nb) ? bsums[t] : 0;
    tmp[t] = v;
    __syncthreads();
    for (int off = 1; off < SCAN_BS; off <<= 1) {
        int x = (t >= off) ? tmp[t - off] : 0;
        __syncthreads();
        tmp[t] += x;
        __syncthreads();
    }
    if (t < nb) bsums[t] = tmp[t] - v;
}

__global__ void ALGN_scan3(int* __restrict__ rowPtr, int* __restrict__ rowOff,
                           const int* __restrict__ bsums, int n, int nE) {
    int g = blockIdx.x * SCAN_BS + threadIdx.x;
    if (g < n) {
        int v = rowPtr[g] + bsums[blockIdx.x];
        rowPtr[g] = v;
        rowOff[g] = v;
    }
    if (g == 0) rowPtr[n] = nE;
}

__global__ void ALGN_fill(const int* __restrict__ rows, const int* __restrict__ cols,
                          const float* __restrict__ vals, int* __restrict__ rowOff,
                          int2* __restrict__ pairs, int nE) {
    int e = blockIdx.x * blockDim.x + threadIdx.x;
    if (e >= nE) return;
    int pos = atomicAdd(&rowOff[rows[e]], 1);
    int2 p;
    p.x = cols[e];
    p.y = __float_as_int(vals[e]);
    pairs[pos] = p;
}

// ---------- demand-set flags (idempotent stores only) ----------
// flagB: batch rows. flag2: batch rows U cols(edges of batch rows).
__global__ void ALGN_mark2(const int* __restrict__ rowPtr, const int2* __restrict__ pairs,
                           const int* __restrict__ users, const int* __restrict__ items,
                           int* __restrict__ flag2, int* __restrict__ flagB,
                           int batch, int nUser) {
    int b = blockIdx.x * blockDim.x + threadIdx.x;
    if (b >= 2 * batch) return;
    int row = (b < batch) ? users[b] : (nUser + items[b - batch]);
    flagB[row] = 1;
    flag2[row] = 1;
    int beg = rowPtr[row], end = rowPtr[row + 1];
    for (int j = beg; j < end; ++j) flag2[pairs[j].x] = 1;
}

// ---------- SpMM row body (16 lanes/row, ushort4/lane, unroll x4) ----------
__device__ __forceinline__ void spmm_row(const ushort4* __restrict__ cur,
                                         ushort4* __restrict__ next,
                                         const int* __restrict__ rowPtr,
                                         const int2* __restrict__ pairs,
                                         int row, int fl) {
    int beg = rowPtr[row];
    int end = rowPtr[row + 1];
    float4 s = make_float4(0.f, 0.f, 0.f, 0.f);
    int j = beg;
    for (; j + 4 <= end; j += 4) {
        int2 e0 = pairs[j + 0];
        int2 e1 = pairs[j + 1];
        int2 e2 = pairs[j + 2];
        int2 e3 = pairs[j + 3];
        ushort4 x0 = cur[(size_t)e0.x * 16 + fl];
        ushort4 x1 = cur[(size_t)e1.x * 16 + fl];
        ushort4 x2 = cur[(size_t)e2.x * 16 + fl];
        ushort4 x3 = cur[(size_t)e3.x * 16 + fl];
        float v0 = __int_as_float(e0.y);
        float v1 = __int_as_float(e1.y);
        float v2 = __int_as_float(e2.y);
        float v3 = __int_as_float(e3.y);
        s.x += v0 * bf2f(x0.x); s.y += v0 * bf2f(x0.y); s.z += v0 * bf2f(x0.z); s.w += v0 * bf2f(x0.w);
        s.x += v1 * bf2f(x1.x); s.y += v1 * bf2f(x1.y); s.z += v1 * bf2f(x1.z); s.w += v1 * bf2f(x1.w);
        s.x += v2 * bf2f(x2.x); s.y += v2 * bf2f(x2.y); s.z += v2 * bf2f(x2.z); s.w += v2 * bf2f(x2.w);
        s.x += v3 * bf2f(x3.x); s.y += v3 * bf2f(x3.y); s.z += v3 * bf2f(x3.z); s.w += v3 * bf2f(x3.w);
    }
    for (; j < end; ++j) {
        int2 e = pairs[j];
        ushort4 x = cur[(size_t)e.x * 16 + fl];
        float v = __int_as_float(e.y);
        s.x += v * bf2f(x.x); s.y += v * bf2f(x.y); s.z += v * bf2f(x.z); s.w += v * bf2f(x.w);
    }
    ushort4 o;
    o.x = f2bf(s.x); o.y = f2bf(s.y); o.z = f2bf(s.z); o.w = f2bf(s.w);
    next[(size_t)row * 16 + fl] = o;
}

// full: one row per 16-lane sub-group
__global__ void ALGN_spmm_csr(const ushort4* __restrict__ cur, ushort4* __restrict__ next,
                              const int* __restrict__ rowPtr, const int2* __restrict__ pairs,
                              int nNodes) {
    int tid = blockIdx.x * blockDim.x + threadIdx.x;
    int row = tid >> 4;
    int fl  = tid & 15;
    if (row >= nNodes) return;
    spmm_row(cur, next, rowPtr, pairs, row, fl);
}

// flag-guarded: full grid, each flagged row computed by exactly one sub-group
__global__ void ALGN_spmm_flag(const ushort4* __restrict__ cur, ushort4* __restrict__ next,
                               const int* __restrict__ rowPtr, const int2* __restrict__ pairs,
                               const int* __restrict__ flag, int nNodes) {
    int tid = blockIdx.x * blockDim.x + threadIdx.x;
    int row = tid >> 4;
    int fl  = tid & 15;
    if (row >= nNodes) return;
    if (!flag[row]) return;
    spmm_row(cur, next, rowPtr, pairs, row, fl);
}

// ---------- batch gather-accumulate (layer mean 0.25 folded per side) -----
__global__ void ALGN_gather_add(const unsigned short* __restrict__ emb,
                                const int* __restrict__ users, const int* __restrict__ items,
                                float* __restrict__ U, float* __restrict__ I,
                                int batch, int nUser) {
    int t = blockIdx.x * blockDim.x + threadIdx.x;
    if (t >= batch * EMB) return;
    int b = t >> 6, c = t & 63;
    U[t] += bf2f(emb[users[b] * EMB + c]) * 0.25f;
    I[t] += bf2f(emb[(nUser + items[b]) * EMB + c]) * 0.25f;
}

// ---------- sigmoid(U @ I^T), 16x16 tile per 256-thread block ----------
__global__ void ALGN_gemm_sigmoid(const float* __restrict__ U, const float* __restrict__ I,
                                  float* __restrict__ out, int B) {
    __shared__ float su[16][EMB + 1];
    __shared__ float si[16][EMB + 1];
    int tx = threadIdx.x, ty = threadIdx.y;
    int row0 = blockIdx.y * 16, col0 = blockIdx.x * 16;
    int tid = ty * 16 + tx;
    for (int k = tid; k < 16 * EMB; k += 256) {
        int r = k >> 6, c = k & 63;
        su[r][c] = U[(row0 + r) * EMB + c];
        si[r][c] = I[(col0 + r) * EMB + c];
    }
    __syncthreads();
    float s = 0.f;
#pragma unroll
    for (int k = 0; k < EMB; ++k) s += su[ty][k] * si[tx][k];
    out[(row0 + ty) * B + (col0 + tx)] = 1.f / (1.f + __expf(-s));
}

extern "C" void kernel_launch(void* const* d_in, const int* in_sizes, int n_in,
                              void* d_out, int out_size, void* d_ws, size_t ws_size,
                              hipStream_t stream) {
    const float* user_emb = (const float*)d_in[0];
    const float* item_emb = (const float*)d_in[1];
    const float* adj_vals = (const float*)d_in[2];
    const int*   adj_rows = (const int*)d_in[3];
    const int*   adj_cols = (const int*)d_in[4];
    const int*   users    = (const int*)d_in[5];
    const int*   items    = (const int*)d_in[6];
    float* out = (float*)d_out;

    const int nUserF = in_sizes[0];
    const int nItemF = in_sizes[1];
    const int nEdges = in_sizes[2];
    const int batch  = in_sizes[5];
    const int nUser  = nUserF / EMB;
    const int totalF = nUserF + nItemF;
    const int nNodes = totalF / EMB;
    const int n4     = totalF / 4;

    unsigned short* embA = (unsigned short*)d_ws;
    unsigned short* embB = embA + totalF;
    float* Ub = (float*)(embB + totalF);
    float* Ib = Ub + (size_t)batch * EMB;
    int2*  pairs = (int2*)(Ib + (size_t)batch * EMB);
    int*   rowPtr = (int*)(pairs + nEdges);
    int*   rowOff = rowPtr + (nNodes + 1);
    int*   bsums  = rowOff + nNodes;
    int*   flag2  = bsums + SCAN_BS;
    int*   flagB  = flag2 + nNodes;

    const int nScanBlocks = (nNodes + SCAN_BS - 1) / SCAN_BS;   // 293 <= 512

    hipMemsetAsync(rowOff, 0, (size_t)nNodes * sizeof(int), stream);
    hipMemsetAsync(Ub, 0, (size_t)batch * EMB * sizeof(float) * 2, stream);   // Ub+Ib
    hipMemsetAsync(flag2, 0, (size_t)nNodes * sizeof(int) * 2, stream);       // flag2+flagB

    ALGN_init_emb<<<(n4 + 255) / 256, 256, 0, stream>>>(
        (const float4*)user_emb, (const float4*)item_emb, (ushort4*)embA, nUserF / 4, n4);

    // ---- CSR build ----
    ALGN_hist<<<(nEdges + 255) / 256, 256, 0, stream>>>(adj_rows, rowOff, nEdges);
    ALGN_scan1<<<nScanBlocks, SCAN_BS, 0, stream>>>(rowOff, rowPtr, bsums, nNodes);
    ALGN_scan2<<<1, SCAN_BS, 0, stream>>>(bsums, nScanBlocks);
    ALGN_scan3<<<nScanBlocks, SCAN_BS, 0, stream>>>(rowPtr, rowOff, bsums, nNodes, nEdges);
    ALGN_fill<<<(nEdges + 255) / 256, 256, 0, stream>>>(
        adj_rows, adj_cols, adj_vals, rowOff, pairs, nEdges);

    // ---- demand-set flags (needs CSR) ----
    ALGN_mark2<<<(2 * batch + 255) / 256, 256, 0, stream>>>(
        rowPtr, pairs, users, items, flag2, flagB, batch, nUser);

    // ---- layer 0 contribution ----
    ALGN_gather_add<<<(batch * EMB + 255) / 256, 256, 0, stream>>>(
        embA, users, items, Ub, Ib, batch, nUser);

    const int fullBlocks = (nNodes * 16 + 255) / 256;

    // ---- layer 1: full (demand set ~ all nodes) ----
    ALGN_spmm_csr<<<fullBlocks, 256, 0, stream>>>(
        (const ushort4*)embA, (ushort4*)embB, rowPtr, pairs, nNodes);
    ALGN_gather_add<<<(batch * EMB + 255) / 256, 256, 0, stream>>>(
        embB, users, items, Ub, Ib, batch, nUser);

    // ---- layer 2: S2 rows only (flag-guarded) ----
    ALGN_spmm_flag<<<fullBlocks, 256, 0, stream>>>(
        (const ushort4*)embB, (ushort4*)embA, rowPtr, pairs, flag2, nNodes);
    ALGN_gather_add<<<(batch * EMB + 255) / 256, 256, 0, stream>>>(
        embA, users, items, Ub, Ib, batch, nUser);

    // ---- layer 3: batch rows only (flag-guarded, no duplicate writers) ----
    ALGN_spmm_flag<<<fullBlocks, 256, 0, stream>>>(
        (const ushort4*)embA, (ushort4*)embB, rowPtr, pairs, flagB, nNodes);
    ALGN_gather_add<<<(batch * EMB + 255) / 256, 256, 0, stream>>>(
        embB, users, items, Ub, Ib, batch, nUser);

    dim3 gg(batch / 16, batch / 16);
    dim3 gb(16, 16);
    ALGN_gemm_sigmoid<<<gg, gb, 0, stream>>>(Ub, Ib, out, batch);
}

// Round 9
// 321.536 us; speedup vs baseline: 16.3786x; 1.5175x over previous
//
#include <hip/hip_runtime.h>
#include <hip/hip_bf16.h>

// LightGCN on MI355X. R9: deterministic bucket-partition CSR build.
// R8 post-mortem: fill (~160 us) is bound by 2M random returning atomics +
// random line-touches over 16 MB, invariant to write bytes; hist adds ~35 us.
// R9 replaces hist+scan+fill with: per-block LDS bucket histograms ->
// deterministic (bucket,block) offset scan -> bucket-contiguous scatter
// (writes in 64 KB windows) -> per-bucket LDS counting sort emitting rowPtr
// + row-sorted pairs. No global atomics in the build; only within-row order
// is nondeterministic (same class as replay-proven R5/R8).
// Propagation unchanged: bf16 tables, backward-sliced layers (full / S2 / B).
//
// d_ws (4B units): embA bf16[totalF] | embB bf16[totalF] | Ub[B*64] |
//   Ib[B*64] | pairs int2[E] | part int2[E] | rowPtr[N+1] |
//   blockHist[NB*BP] | bucketTotal[NB] | bucketBase[NB+1] | flag2[N] |
//   flagB[N]   (~74 MB; 95 MB proven available)

#define EMB 64
#define NB 512          // destination-node buckets (293 rows each)
#define BP 512          // partition blocks (edge segments)

__device__ __forceinline__ float bf2f(unsigned short u) {
    union { unsigned int i; float f; } v;
    v.i = ((unsigned int)u) << 16;
    return v.f;
}
__device__ __forceinline__ unsigned short f2bf(float f) {
    union { float f; unsigned int i; } v;
    v.f = f;
    unsigned int lsb = (v.i >> 16) & 1;
    v.i += 0x7fffu + lsb;          // round-to-nearest-even
    return (unsigned short)(v.i >> 16);
}

// ---------- init: concat(user_emb, item_emb) -> bf16 embA ----------
__global__ void ALGN_init_emb(const float4* __restrict__ ue, const float4* __restrict__ ie,
                              ushort4* __restrict__ emb, int nUser4, int n4) {
    int t = blockIdx.x * blockDim.x + threadIdx.x;
    if (t >= n4) return;
    float4 v = (t < nUser4) ? ue[t] : ie[t - nUser4];
    ushort4 o;
    o.x = f2bf(v.x); o.y = f2bf(v.y); o.z = f2bf(v.z); o.w = f2bf(v.w);
    emb[t] = o;
}

// ---------- partition pass 1: per-(block,bucket) edge counts ----------
__global__ void ALGN_p1(const int* __restrict__ rows, int* __restrict__ blockHist,
                        int nE, int seg, int bsz) {
    __shared__ int h[NB];
    int blk = blockIdx.x;
    for (int i = threadIdx.x; i < NB; i += blockDim.x) h[i] = 0;
    __syncthreads();
    int beg = blk * seg, end = min(beg + seg, nE);
    for (int e = beg + threadIdx.x; e < end; e += blockDim.x)
        atomicAdd(&h[rows[e] / bsz], 1);
    __syncthreads();
    for (int u = threadIdx.x; u < NB; u += blockDim.x)
        blockHist[u * BP + blk] = h[u];          // bucket-major
}

// ---------- scanA: per bucket, exclusive scan across blocks ----------
__global__ void ALGN_scanA(int* __restrict__ blockHist, int* __restrict__ bucketTotal) {
    __shared__ int tmp[BP];
    int b = blockIdx.x, t = threadIdx.x;
    int v = blockHist[b * BP + t];
    tmp[t] = v;
    __syncthreads();
    for (int off = 1; off < BP; off <<= 1) {
        int x = (t >= off) ? tmp[t - off] : 0;
        __syncthreads();
        tmp[t] += x;
        __syncthreads();
    }
    blockHist[b * BP + t] = tmp[t] - v;          // exclusive over blocks
    if (t == BP - 1) bucketTotal[b] = tmp[t];
}

// ---------- scanB: exclusive scan of bucket totals -> bases ----------
__global__ void ALGN_scanB(const int* __restrict__ bucketTotal, int* __restrict__ bucketBase) {
    __shared__ int tmp[NB];
    int t = threadIdx.x;
    int v = bucketTotal[t];
    tmp[t] = v;
    __syncthreads();
    for (int off = 1; off < NB; off <<= 1) {
        int x = (t >= off) ? tmp[t - off] : 0;
        __syncthreads();
        tmp[t] += x;
        __syncthreads();
    }
    bucketBase[t] = tmp[t] - v;
    if (t == NB - 1) bucketBase[NB] = tmp[t];    // = nE
}

// ---------- partition pass 2: scatter packed records, LDS cursors ----------
// record: x = (localRow<<18) | col  (localRow<512, col<2^18), y = val bits
__global__ void ALGN_p2(const int* __restrict__ rows, const int* __restrict__ cols,
                        const float* __restrict__ vals,
                        const int* __restrict__ blockHist, const int* __restrict__ bucketBase,
                        int2* __restrict__ part, int nE, int seg, int bsz) {
    __shared__ int cur[NB];
    int blk = blockIdx.x;
    for (int u = threadIdx.x; u < NB; u += blockDim.x)
        cur[u] = bucketBase[u] + blockHist[u * BP + blk];
    __syncthreads();
    int beg = blk * seg, end = min(beg + seg, nE);
    for (int e = beg + threadIdx.x; e < end; e += blockDim.x) {
        int r = rows[e];
        int u = r / bsz;
        int pos = atomicAdd(&cur[u], 1);         // exact range by construction
        int lr = r - u * bsz;
        part[pos] = make_int2((lr << 18) | cols[e], __float_as_int(vals[e]));
    }
}

// ---------- per-bucket counting sort -> rowPtr + row-sorted pairs ----------
__global__ void ALGN_bsort(const int2* __restrict__ part, const int* __restrict__ bucketBase,
                           int2* __restrict__ pairs, int* __restrict__ rowPtr,
                           int nNodes, int bsz, int nE) {
    __shared__ int st[NB];                       // NB >= bsz
    int b = blockIdx.x, t = threadIdx.x;
    int base = bucketBase[b], lim = bucketBase[b + 1];
    st[t] = 0;
    __syncthreads();
    for (int j = base + t; j < lim; j += blockDim.x)
        atomicAdd(&st[part[j].x >> 18], 1);
    __syncthreads();
    int v = st[t];
    for (int off = 1; off < NB; off <<= 1) {     // inclusive scan in place
        int x = (t >= off) ? st[t - off] : 0;
        __syncthreads();
        st[t] += x;
        __syncthreads();
    }
    int excl = st[t] - v;
    __syncthreads();
    st[t] = excl;                                // now exclusive starts / cursors
    __syncthreads();
    int row = b * bsz + t;
    if (t < bsz && row < nNodes) rowPtr[row] = base + excl;
    if (b == NB - 1 && t == 0) rowPtr[nNodes] = nE;
    for (int j = base + t; j < lim; j += blockDim.x) {
        int2 p = part[j];
        int lr = p.x >> 18;
        int pos = base + atomicAdd(&st[lr], 1);
        pairs[pos] = make_int2(p.x & 0x3FFFF, p.y);
    }
}

// ---------- demand-set flags (idempotent stores only) ----------
__global__ void ALGN_mark2(const int* __restrict__ rowPtr, const int2* __restrict__ pairs,
                           const int* __restrict__ users, const int* __restrict__ items,
                           int* __restrict__ flag2, int* __restrict__ flagB,
                           int batch, int nUser) {
    int b = blockIdx.x * blockDim.x + threadIdx.x;
    if (b >= 2 * batch) return;
    int row = (b < batch) ? users[b] : (nUser + items[b - batch]);
    flagB[row] = 1;
    flag2[row] = 1;
    int beg = rowPtr[row], end = rowPtr[row + 1];
    for (int j = beg; j < end; ++j) flag2[pairs[j].x] = 1;
}

// ---------- SpMM row body (16 lanes/row, ushort4/lane, unroll x4) ----------
__device__ __forceinline__ void spmm_row(const ushort4* __restrict__ cur,
                                         ushort4* __restrict__ next,
                                         const int* __restrict__ rowPtr,
                                         const int2* __restrict__ pairs,
                                         int row, int fl) {
    int beg = rowPtr[row];
    int end = rowPtr[row + 1];
    float4 s = make_float4(0.f, 0.f, 0.f, 0.f);
    int j = beg;
    for (; j + 4 <= end; j += 4) {
        int2 e0 = pairs[j + 0];
        int2 e1 = pairs[j + 1];
        int2 e2 = pairs[j + 2];
        int2 e3 = pairs[j + 3];
        ushort4 x0 = cur[(size_t)e0.x * 16 + fl];
        ushort4 x1 = cur[(size_t)e1.x * 16 + fl];
        ushort4 x2 = cur[(size_t)e2.x * 16 + fl];
        ushort4 x3 = cur[(size_t)e3.x * 16 + fl];
        float v0 = __int_as_float(e0.y);
        float v1 = __int_as_float(e1.y);
        float v2 = __int_as_float(e2.y);
        float v3 = __int_as_float(e3.y);
        s.x += v0 * bf2f(x0.x); s.y += v0 * bf2f(x0.y); s.z += v0 * bf2f(x0.z); s.w += v0 * bf2f(x0.w);
        s.x += v1 * bf2f(x1.x); s.y += v1 * bf2f(x1.y); s.z += v1 * bf2f(x1.z); s.w += v1 * bf2f(x1.w);
        s.x += v2 * bf2f(x2.x); s.y += v2 * bf2f(x2.y); s.z += v2 * bf2f(x2.z); s.w += v2 * bf2f(x2.w);
        s.x += v3 * bf2f(x3.x); s.y += v3 * bf2f(x3.y); s.z += v3 * bf2f(x3.z); s.w += v3 * bf2f(x3.w);
    }
    for (; j < end; ++j) {
        int2 e = pairs[j];
        ushort4 x = cur[(size_t)e.x * 16 + fl];
        float v = __int_as_float(e.y);
        s.x += v * bf2f(x.x); s.y += v * bf2f(x.y); s.z += v * bf2f(x.z); s.w += v * bf2f(x.w);
    }
    ushort4 o;
    o.x = f2bf(s.x); o.y = f2bf(s.y); o.z = f2bf(s.z); o.w = f2bf(s.w);
    next[(size_t)row * 16 + fl] = o;
}

__global__ void ALGN_spmm_csr(const ushort4* __restrict__ cur, ushort4* __restrict__ next,
                              const int* __restrict__ rowPtr, const int2* __restrict__ pairs,
                              int nNodes) {
    int tid = blockIdx.x * blockDim.x + threadIdx.x;
    int row = tid >> 4;
    int fl  = tid & 15;
    if (row >= nNodes) return;
    spmm_row(cur, next, rowPtr, pairs, row, fl);
}

__global__ void ALGN_spmm_flag(const ushort4* __restrict__ cur, ushort4* __restrict__ next,
                               const int* __restrict__ rowPtr, const int2* __restrict__ pairs,
                               const int* __restrict__ flag, int nNodes) {
    int tid = blockIdx.x * blockDim.x + threadIdx.x;
    int row = tid >> 4;
    int fl  = tid & 15;
    if (row >= nNodes) return;
    if (!flag[row]) return;
    spmm_row(cur, next, rowPtr, pairs, row, fl);
}

// ---------- batch gather-accumulate (layer mean 0.25 folded per side) -----
__global__ void ALGN_gather_add(const unsigned short* __restrict__ emb,
                                const int* __restrict__ users, const int* __restrict__ items,
                                float* __restrict__ U, float* __restrict__ I,
                                int batch, int nUser) {
    int t = blockIdx.x * blockDim.x + threadIdx.x;
    if (t >= batch * EMB) return;
    int b = t >> 6, c = t & 63;
    U[t] += bf2f(emb[users[b] * EMB + c]) * 0.25f;
    I[t] += bf2f(emb[(nUser + items[b]) * EMB + c]) * 0.25f;
}

// ---------- sigmoid(U @ I^T), 16x16 tile per 256-thread block ----------
__global__ void ALGN_gemm_sigmoid(const float* __restrict__ U, const float* __restrict__ I,
                                  float* __restrict__ out, int B) {
    __shared__ float su[16][EMB + 1];
    __shared__ float si[16][EMB + 1];
    int tx = threadIdx.x, ty = threadIdx.y;
    int row0 = blockIdx.y * 16, col0 = blockIdx.x * 16;
    int tid = ty * 16 + tx;
    for (int k = tid; k < 16 * EMB; k += 256) {
        int r = k >> 6, c = k & 63;
        su[r][c] = U[(row0 + r) * EMB + c];
        si[r][c] = I[(col0 + r) * EMB + c];
    }
    __syncthreads();
    float s = 0.f;
#pragma unroll
    for (int k = 0; k < EMB; ++k) s += su[ty][k] * si[tx][k];
    out[(row0 + ty) * B + (col0 + tx)] = 1.f / (1.f + __expf(-s));
}

extern "C" void kernel_launch(void* const* d_in, const int* in_sizes, int n_in,
                              void* d_out, int out_size, void* d_ws, size_t ws_size,
                              hipStream_t stream) {
    const float* user_emb = (const float*)d_in[0];
    const float* item_emb = (const float*)d_in[1];
    const float* adj_vals = (const float*)d_in[2];
    const int*   adj_rows = (const int*)d_in[3];
    const int*   adj_cols = (const int*)d_in[4];
    const int*   users    = (const int*)d_in[5];
    const int*   items    = (const int*)d_in[6];
    float* out = (float*)d_out;

    const int nUserF = in_sizes[0];
    const int nItemF = in_sizes[1];
    const int nEdges = in_sizes[2];
    const int batch  = in_sizes[5];
    const int nUser  = nUserF / EMB;
    const int totalF = nUserF + nItemF;
    const int nNodes = totalF / EMB;
    const int n4     = totalF / 4;
    const int bsz    = (nNodes + NB - 1) / NB;       // 293
    const int seg    = (nEdges + BP - 1) / BP;       // 3907

    unsigned short* embA = (unsigned short*)d_ws;
    unsigned short* embB = embA + totalF;
    float* Ub = (float*)(embB + totalF);
    float* Ib = Ub + (size_t)batch * EMB;
    int2*  pairs = (int2*)(Ib + (size_t)batch * EMB);
    int2*  part  = pairs + nEdges;
    int*   rowPtr = (int*)(part + nEdges);
    int*   blockHist   = rowPtr + (nNodes + 1);
    int*   bucketTotal = blockHist + NB * BP;
    int*   bucketBase  = bucketTotal + NB;
    int*   flag2 = bucketBase + (NB + 1);
    int*   flagB = flag2 + nNodes;

    hipMemsetAsync(Ub, 0, (size_t)batch * EMB * sizeof(float) * 2, stream);   // Ub+Ib
    hipMemsetAsync(flag2, 0, (size_t)nNodes * sizeof(int) * 2, stream);       // flag2+flagB

    ALGN_init_emb<<<(n4 + 255) / 256, 256, 0, stream>>>(
        (const float4*)user_emb, (const float4*)item_emb, (ushort4*)embA, nUserF / 4, n4);

    // ---- deterministic CSR build ----
    ALGN_p1<<<BP, 256, 0, stream>>>(adj_rows, blockHist, nEdges, seg, bsz);
    ALGN_scanA<<<NB, BP, 0, stream>>>(blockHist, bucketTotal);
    ALGN_scanB<<<1, NB, 0, stream>>>(bucketTotal, bucketBase);
    ALGN_p2<<<BP, 256, 0, stream>>>(adj_rows, adj_cols, adj_vals,
                                    blockHist, bucketBase, part, nEdges, seg, bsz);
    ALGN_bsort<<<NB, NB, 0, stream>>>(part, bucketBase, pairs, rowPtr, nNodes, bsz, nEdges);

    // ---- demand-set flags ----
    ALGN_mark2<<<(2 * batch + 255) / 256, 256, 0, stream>>>(
        rowPtr, pairs, users, items, flag2, flagB, batch, nUser);

    // ---- layer 0 contribution ----
    ALGN_gather_add<<<(batch * EMB + 255) / 256, 256, 0, stream>>>(
        embA, users, items, Ub, Ib, batch, nUser);

    const int fullBlocks = (nNodes * 16 + 255) / 256;

    // ---- layer 1: full ----
    ALGN_spmm_csr<<<fullBlocks, 256, 0, stream>>>(
        (const ushort4*)embA, (ushort4*)embB, rowPtr, pairs, nNodes);
    ALGN_gather_add<<<(batch * EMB + 255) / 256, 256, 0, stream>>>(
        embB, users, items, Ub, Ib, batch, nUser);

    // ---- layer 2: S2 rows only ----
    ALGN_spmm_flag<<<fullBlocks, 256, 0, stream>>>(
        (const ushort4*)embB, (ushort4*)embA, rowPtr, pairs, flag2, nNodes);
    ALGN_gather_add<<<(batch * EMB + 255) / 256, 256, 0, stream>>>(
        embA, users, items, Ub, Ib, batch, nUser);

    // ---- layer 3: batch rows only ----
    ALGN_spmm_flag<<<fullBlocks, 256, 0, stream>>>(
        (const ushort4*)embA, (ushort4*)embB, rowPtr, pairs, flagB, nNodes);
    ALGN_gather_add<<<(batch * EMB + 255) / 256, 256, 0, stream>>>(
        embB, users, items, Ub, Ib, batch, nUser);

    dim3 gg(batch / 16, batch / 16);
    dim3 gb(16, 16);
    ALGN_gemm_sigmoid<<<gg, gb, 0, stream>>>(Ub, Ib, out, batch);
}

// Round 10
// 306.629 us; speedup vs baseline: 17.1749x; 1.0486x over previous
//
#include <hip/hip_runtime.h>
#include <hip/hip_bf16.h>

// LightGCN on MI355X. R10: occupancy for the latency-bound build + bigger
// sigmoid-GEMM tile.
// R9 post-mortem: p2 45 us at 14.6% occupancy / 3% VALU (latency-bound,
// BP=512 -> 8 waves/CU peak); spmm_csr 45 us (L3 random-gather bound,
// FETCH 113 MB for a 19 MB table); everything else <45 us.
// R10: BP 512->1024 (p1/p2 2x parallelism), bsort 1024 threads,
// gemm_sigmoid 32x32 tile (4 out/thread). Build stays deterministic; only
// within-row edge order nondeterministic (replay-proven class).
//
// d_ws (4B units): embA bf16[totalF] | embB bf16[totalF] | Ub[B*64] |
//   Ib[B*64] | pairs int2[E] | part int2[E] | rowPtr[N+1] |
//   blockHist[NB*BP] | bucketTotal[NB] | bucketBase[NB+1] | flag2[N] |
//   flagB[N]   (~77 MB; 95 MB proven available)

#define EMB 64
#define NB 512          // destination-node buckets (293 rows each)
#define BP 1024         // partition blocks (edge segments)

__device__ __forceinline__ float bf2f(unsigned short u) {
    union { unsigned int i; float f; } v;
    v.i = ((unsigned int)u) << 16;
    return v.f;
}
__device__ __forceinline__ unsigned short f2bf(float f) {
    union { float f; unsigned int i; } v;
    v.f = f;
    unsigned int lsb = (v.i >> 16) & 1;
    v.i += 0x7fffu + lsb;          // round-to-nearest-even
    return (unsigned short)(v.i >> 16);
}

// ---------- init: concat(user_emb, item_emb) -> bf16 embA ----------
__global__ void ALGN_init_emb(const float4* __restrict__ ue, const float4* __restrict__ ie,
                              ushort4* __restrict__ emb, int nUser4, int n4) {
    int t = blockIdx.x * blockDim.x + threadIdx.x;
    if (t >= n4) return;
    float4 v = (t < nUser4) ? ue[t] : ie[t - nUser4];
    ushort4 o;
    o.x = f2bf(v.x); o.y = f2bf(v.y); o.z = f2bf(v.z); o.w = f2bf(v.w);
    emb[t] = o;
}

// ---------- partition pass 1: per-(block,bucket) edge counts ----------
__global__ void ALGN_p1(const int* __restrict__ rows, int* __restrict__ blockHist,
                        int nE, int seg, int bsz) {
    __shared__ int h[NB];
    int blk = blockIdx.x;
    for (int i = threadIdx.x; i < NB; i += blockDim.x) h[i] = 0;
    __syncthreads();
    int beg = blk * seg, end = min(beg + seg, nE);
    for (int e = beg + threadIdx.x; e < end; e += blockDim.x)
        atomicAdd(&h[rows[e] / bsz], 1);
    __syncthreads();
    for (int u = threadIdx.x; u < NB; u += blockDim.x)
        blockHist[u * BP + blk] = h[u];          // bucket-major
}

// ---------- scanA: per bucket, exclusive scan across blocks ----------
__global__ void ALGN_scanA(int* __restrict__ blockHist, int* __restrict__ bucketTotal) {
    __shared__ int tmp[BP];
    int b = blockIdx.x, t = threadIdx.x;
    int v = blockHist[b * BP + t];
    tmp[t] = v;
    __syncthreads();
    for (int off = 1; off < BP; off <<= 1) {
        int x = (t >= off) ? tmp[t - off] : 0;
        __syncthreads();
        tmp[t] += x;
        __syncthreads();
    }
    blockHist[b * BP + t] = tmp[t] - v;          // exclusive over blocks
    if (t == BP - 1) bucketTotal[b] = tmp[t];
}

// ---------- scanB: exclusive scan of bucket totals -> bases ----------
__global__ void ALGN_scanB(const int* __restrict__ bucketTotal, int* __restrict__ bucketBase) {
    __shared__ int tmp[NB];
    int t = threadIdx.x;
    int v = bucketTotal[t];
    tmp[t] = v;
    __syncthreads();
    for (int off = 1; off < NB; off <<= 1) {
        int x = (t >= off) ? tmp[t - off] : 0;
        __syncthreads();
        tmp[t] += x;
        __syncthreads();
    }
    bucketBase[t] = tmp[t] - v;
    if (t == NB - 1) bucketBase[NB] = tmp[t];    // = nE
}

// ---------- partition pass 2: scatter packed records, LDS cursors ----------
// record: x = (localRow<<18) | col  (localRow<512, col<2^18), y = val bits
__global__ void ALGN_p2(const int* __restrict__ rows, const int* __restrict__ cols,
                        const float* __restrict__ vals,
                        const int* __restrict__ blockHist, const int* __restrict__ bucketBase,
                        int2* __restrict__ part, int nE, int seg, int bsz) {
    __shared__ int cur[NB];
    int blk = blockIdx.x;
    for (int u = threadIdx.x; u < NB; u += blockDim.x)
        cur[u] = bucketBase[u] + blockHist[u * BP + blk];
    __syncthreads();
    int beg = blk * seg, end = min(beg + seg, nE);
    for (int e = beg + threadIdx.x; e < end; e += blockDim.x) {
        int r = rows[e];
        int u = r / bsz;
        int pos = atomicAdd(&cur[u], 1);         // exact range by construction
        int lr = r - u * bsz;
        part[pos] = make_int2((lr << 18) | cols[e], __float_as_int(vals[e]));
    }
}

// ---------- per-bucket counting sort -> rowPtr + row-sorted pairs ----------
// blockDim = 1024; st[] has NB entries, guarded; barriers unconditional.
__global__ void ALGN_bsort(const int2* __restrict__ part, const int* __restrict__ bucketBase,
                           int2* __restrict__ pairs, int* __restrict__ rowPtr,
                           int nNodes, int bsz, int nE) {
    __shared__ int st[NB];
    int b = blockIdx.x, t = threadIdx.x;
    int base = bucketBase[b], lim = bucketBase[b + 1];
    if (t < NB) st[t] = 0;
    __syncthreads();
    for (int j = base + t; j < lim; j += blockDim.x)
        atomicAdd(&st[part[j].x >> 18], 1);
    __syncthreads();
    int v = (t < NB) ? st[t] : 0;
    for (int off = 1; off < NB; off <<= 1) {     // inclusive scan over NB entries
        int x = (t >= off && t < NB) ? st[t - off] : 0;
        __syncthreads();
        if (t < NB) st[t] += x;
        __syncthreads();
    }
    int excl = (t < NB) ? st[t] - v : 0;
    __syncthreads();
    if (t < NB) st[t] = excl;                    // exclusive starts / cursors
    __syncthreads();
    int row = b * bsz + t;
    if (t < bsz && row < nNodes) rowPtr[row] = base + excl;
    if (b == NB - 1 && t == 0) rowPtr[nNodes] = nE;
    for (int j = base + t; j < lim; j += blockDim.x) {
        int2 p = part[j];
        int lr = p.x >> 18;
        int pos = base + atomicAdd(&st[lr], 1);
        pairs[pos] = make_int2(p.x & 0x3FFFF, p.y);
    }
}

// ---------- demand-set flags (idempotent stores only) ----------
__global__ void ALGN_mark2(const int* __restrict__ rowPtr, const int2* __restrict__ pairs,
                           const int* __restrict__ users, const int* __restrict__ items,
                           int* __restrict__ flag2, int* __restrict__ flagB,
                           int batch, int nUser) {
    int b = blockIdx.x * blockDim.x + threadIdx.x;
    if (b >= 2 * batch) return;
    int row = (b < batch) ? users[b] : (nUser + items[b - batch]);
    flagB[row] = 1;
    flag2[row] = 1;
    int beg = rowPtr[row], end = rowPtr[row + 1];
    for (int j = beg; j < end; ++j) flag2[pairs[j].x] = 1;
}

// ---------- SpMM row body (16 lanes/row, ushort4/lane, unroll x4) ----------
__device__ __forceinline__ void spmm_row(const ushort4* __restrict__ cur,
                                         ushort4* __restrict__ next,
                                         const int* __restrict__ rowPtr,
                                         const int2* __restrict__ pairs,
                                         int row, int fl) {
    int beg = rowPtr[row];
    int end = rowPtr[row + 1];
    float4 s = make_float4(0.f, 0.f, 0.f, 0.f);
    int j = beg;
    for (; j + 4 <= end; j += 4) {
        int2 e0 = pairs[j + 0];
        int2 e1 = pairs[j + 1];
        int2 e2 = pairs[j + 2];
        int2 e3 = pairs[j + 3];
        ushort4 x0 = cur[(size_t)e0.x * 16 + fl];
        ushort4 x1 = cur[(size_t)e1.x * 16 + fl];
        ushort4 x2 = cur[(size_t)e2.x * 16 + fl];
        ushort4 x3 = cur[(size_t)e3.x * 16 + fl];
        float v0 = __int_as_float(e0.y);
        float v1 = __int_as_float(e1.y);
        float v2 = __int_as_float(e2.y);
        float v3 = __int_as_float(e3.y);
        s.x += v0 * bf2f(x0.x); s.y += v0 * bf2f(x0.y); s.z += v0 * bf2f(x0.z); s.w += v0 * bf2f(x0.w);
        s.x += v1 * bf2f(x1.x); s.y += v1 * bf2f(x1.y); s.z += v1 * bf2f(x1.z); s.w += v1 * bf2f(x1.w);
        s.x += v2 * bf2f(x2.x); s.y += v2 * bf2f(x2.y); s.z += v2 * bf2f(x2.z); s.w += v2 * bf2f(x2.w);
        s.x += v3 * bf2f(x3.x); s.y += v3 * bf2f(x3.y); s.z += v3 * bf2f(x3.z); s.w += v3 * bf2f(x3.w);
    }
    for (; j < end; ++j) {
        int2 e = pairs[j];
        ushort4 x = cur[(size_t)e.x * 16 + fl];
        float v = __int_as_float(e.y);
        s.x += v * bf2f(x.x); s.y += v * bf2f(x.y); s.z += v * bf2f(x.z); s.w += v * bf2f(x.w);
    }
    ushort4 o;
    o.x = f2bf(s.x); o.y = f2bf(s.y); o.z = f2bf(s.z); o.w = f2bf(s.w);
    next[(size_t)row * 16 + fl] = o;
}

__global__ void ALGN_spmm_csr(const ushort4* __restrict__ cur, ushort4* __restrict__ next,
                              const int* __restrict__ rowPtr, const int2* __restrict__ pairs,
                              int nNodes) {
    int tid = blockIdx.x * blockDim.x + threadIdx.x;
    int row = tid >> 4;
    int fl  = tid & 15;
    if (row >= nNodes) return;
    spmm_row(cur, next, rowPtr, pairs, row, fl);
}

__global__ void ALGN_spmm_flag(const ushort4* __restrict__ cur, ushort4* __restrict__ next,
                               const int* __restrict__ rowPtr, const int2* __restrict__ pairs,
                               const int* __restrict__ flag, int nNodes) {
    int tid = blockIdx.x * blockDim.x + threadIdx.x;
    int row = tid >> 4;
    int fl  = tid & 15;
    if (row >= nNodes) return;
    if (!flag[row]) return;
    spmm_row(cur, next, rowPtr, pairs, row, fl);
}

// ---------- batch gather-accumulate (layer mean 0.25 folded per side) -----
__global__ void ALGN_gather_add(const unsigned short* __restrict__ emb,
                                const int* __restrict__ users, const int* __restrict__ items,
                                float* __restrict__ U, float* __restrict__ I,
                                int batch, int nUser) {
    int t = blockIdx.x * blockDim.x + threadIdx.x;
    if (t >= batch * EMB) return;
    int b = t >> 6, c = t & 63;
    U[t] += bf2f(emb[users[b] * EMB + c]) * 0.25f;
    I[t] += bf2f(emb[(nUser + items[b]) * EMB + c]) * 0.25f;
}

// ---------- sigmoid(U @ I^T): 32x32 tile, 256 threads, 2x2 out/thread ----
__global__ void ALGN_gemm_sigmoid(const float* __restrict__ U, const float* __restrict__ I,
                                  float* __restrict__ out, int B) {
    __shared__ float su[32][EMB + 1];
    __shared__ float si[32][EMB + 1];
    int tx = threadIdx.x, ty = threadIdx.y;     // 16x16
    int row0 = blockIdx.y * 32, col0 = blockIdx.x * 32;
    int tid = ty * 16 + tx;
    for (int k = tid; k < 32 * EMB; k += 256) {
        int r = k >> 6, c = k & 63;
        su[r][c] = U[(row0 + r) * EMB + c];
        si[r][c] = I[(col0 + r) * EMB + c];
    }
    __syncthreads();
    float s00 = 0.f, s01 = 0.f, s10 = 0.f, s11 = 0.f;
#pragma unroll
    for (int k = 0; k < EMB; ++k) {
        float a0 = su[2 * ty][k],     a1 = su[2 * ty + 1][k];
        float b0 = si[2 * tx][k],     b1 = si[2 * tx + 1][k];
        s00 += a0 * b0; s01 += a0 * b1;
        s10 += a1 * b0; s11 += a1 * b1;
    }
    int r0 = row0 + 2 * ty, c0 = col0 + 2 * tx;
    out[(size_t)r0 * B + c0]           = 1.f / (1.f + __expf(-s00));
    out[(size_t)r0 * B + c0 + 1]       = 1.f / (1.f + __expf(-s01));
    out[(size_t)(r0 + 1) * B + c0]     = 1.f / (1.f + __expf(-s10));
    out[(size_t)(r0 + 1) * B + c0 + 1] = 1.f / (1.f + __expf(-s11));
}

extern "C" void kernel_launch(void* const* d_in, const int* in_sizes, int n_in,
                              void* d_out, int out_size, void* d_ws, size_t ws_size,
                              hipStream_t stream) {
    const float* user_emb = (const float*)d_in[0];
    const float* item_emb = (const float*)d_in[1];
    const float* adj_vals = (const float*)d_in[2];
    const int*   adj_rows = (const int*)d_in[3];
    const int*   adj_cols = (const int*)d_in[4];
    const int*   users    = (const int*)d_in[5];
    const int*   items    = (const int*)d_in[6];
    float* out = (float*)d_out;

    const int nUserF = in_sizes[0];
    const int nItemF = in_sizes[1];
    const int nEdges = in_sizes[2];
    const int batch  = in_sizes[5];
    const int nUser  = nUserF / EMB;
    const int totalF = nUserF + nItemF;
    const int nNodes = totalF / EMB;
    const int n4     = totalF / 4;
    const int bsz    = (nNodes + NB - 1) / NB;       // 293
    const int seg    = (nEdges + BP - 1) / BP;       // 1954

    unsigned short* embA = (unsigned short*)d_ws;
    unsigned short* embB = embA + totalF;
    float* Ub = (float*)(embB + totalF);
    float* Ib = Ub + (size_t)batch * EMB;
    int2*  pairs = (int2*)(Ib + (size_t)batch * EMB);
    int2*  part  = pairs + nEdges;
    int*   rowPtr = (int*)(part + nEdges);
    int*   blockHist   = rowPtr + (nNodes + 1);
    int*   bucketTotal = blockHist + NB * BP;
    int*   bucketBase  = bucketTotal + NB;
    int*   flag2 = bucketBase + (NB + 1);
    int*   flagB = flag2 + nNodes;

    hipMemsetAsync(Ub, 0, (size_t)batch * EMB * sizeof(float) * 2, stream);   // Ub+Ib
    hipMemsetAsync(flag2, 0, (size_t)nNodes * sizeof(int) * 2, stream);       // flag2+flagB

    ALGN_init_emb<<<(n4 + 255) / 256, 256, 0, stream>>>(
        (const float4*)user_emb, (const float4*)item_emb, (ushort4*)embA, nUserF / 4, n4);

    // ---- deterministic CSR build ----
    ALGN_p1<<<BP, 256, 0, stream>>>(adj_rows, blockHist, nEdges, seg, bsz);
    ALGN_scanA<<<NB, BP, 0, stream>>>(blockHist, bucketTotal);
    ALGN_scanB<<<1, NB, 0, stream>>>(bucketTotal, bucketBase);
    ALGN_p2<<<BP, 256, 0, stream>>>(adj_rows, adj_cols, adj_vals,
                                    blockHist, bucketBase, part, nEdges, seg, bsz);
    ALGN_bsort<<<NB, 1024, 0, stream>>>(part, bucketBase, pairs, rowPtr, nNodes, bsz, nEdges);

    // ---- demand-set flags ----
    ALGN_mark2<<<(2 * batch + 255) / 256, 256, 0, stream>>>(
        rowPtr, pairs, users, items, flag2, flagB, batch, nUser);

    // ---- layer 0 contribution ----
    ALGN_gather_add<<<(batch * EMB + 255) / 256, 256, 0, stream>>>(
        embA, users, items, Ub, Ib, batch, nUser);

    const int fullBlocks = (nNodes * 16 + 255) / 256;

    // ---- layer 1: full ----
    ALGN_spmm_csr<<<fullBlocks, 256, 0, stream>>>(
        (const ushort4*)embA, (ushort4*)embB, rowPtr, pairs, nNodes);
    ALGN_gather_add<<<(batch * EMB + 255) / 256, 256, 0, stream>>>(
        embB, users, items, Ub, Ib, batch, nUser);

    // ---- layer 2: S2 rows only ----
    ALGN_spmm_flag<<<fullBlocks, 256, 0, stream>>>(
        (const ushort4*)embB, (ushort4*)embA, rowPtr, pairs, flag2, nNodes);
    ALGN_gather_add<<<(batch * EMB + 255) / 256, 256, 0, stream>>>(
        embA, users, items, Ub, Ib, batch, nUser);

    // ---- layer 3: batch rows only ----
    ALGN_spmm_flag<<<fullBlocks, 256, 0, stream>>>(
        (const ushort4*)embA, (ushort4*)embB, rowPtr, pairs, flagB, nNodes);
    ALGN_gather_add<<<(batch * EMB + 255) / 256, 256, 0, stream>>>(
        embB, users, items, Ub, Ib, batch, nUser);

    dim3 gg(batch / 32, batch / 32);
    dim3 gb(16, 16);
    ALGN_gemm_sigmoid<<<gg, gb, 0, stream>>>(Ub, Ib, out, batch);
}

// Round 11
// 285.347 us; speedup vs baseline: 18.4558x; 1.0746x over previous
//
#include <hip/hip_runtime.h>
#include <hip/hip_bf16.h>

// LightGCN on MI355X. R11: SpMM MLP x2 + tail shrink.
// R10 post-mortem: spmm_csr pinned at 45 us / FETCH 113.8 MB (= 8 XCDs x
// ~full 19.2 MB table sweep; bytes structural). Open question: latency-bound
// (more lines in flight helps) vs L2-fill-bound (1 line/cy/XCD ceiling).
// R11: (1) spmm 8 lanes/row, uint4=8bf16/lane, unroll x4 -> 32 lines in
// flight/wave (was 16); (2) pow-2 buckets (bsz=512) -> shifts not divides;
// (3) wave-shfl scans (2 barriers, was ~20); (4) 19 -> 13 dispatches
// (flags zeroed in init_emb, layer-0 gather assigns, mark2 16-lane).
//
// d_ws (4B units): embA bf16[totalF] | embB bf16[totalF] | Ub[B*64] |
//   Ib[B*64] | pairs int2[E] | part int2[E] | rowPtr[N+1] |
//   blockHist[NBMAX*BP] | bucketTotal[NBMAX] | bucketBase[NBMAX+1] |
//   flag2[N] | flagB[N]   (~77 MB; 95 MB proven available)

#define EMB 64
#define BSZ 512         // rows per bucket (pow2: lr = r&511, u = r>>9)
#define NBMAX 512       // max buckets (actual: ceil(150000/512)=293)
#define BP 1024         // partition blocks (edge segments)

__device__ __forceinline__ float bf2f_lo(unsigned int u) {
    return __int_as_float((int)(u << 16));
}
__device__ __forceinline__ float bf2f_hi(unsigned int u) {
    return __int_as_float((int)(u & 0xFFFF0000u));
}
__device__ __forceinline__ float bf2f(unsigned short u) {
    return __int_as_float(((int)u) << 16);
}
__device__ __forceinline__ unsigned short f2bf(float f) {
    union { float f; unsigned int i; } v;
    v.f = f;
    unsigned int lsb = (v.i >> 16) & 1;
    v.i += 0x7fffu + lsb;          // round-to-nearest-even
    return (unsigned short)(v.i >> 16);
}
__device__ __forceinline__ unsigned int pack2(float a, float b) {
    return (unsigned int)f2bf(a) | ((unsigned int)f2bf(b) << 16);
}

// inclusive scan across a 64-lane wave (no barriers)
__device__ __forceinline__ int wave_iscan(int v) {
    int lane = threadIdx.x & 63;
#pragma unroll
    for (int off = 1; off < 64; off <<= 1) {
        int x = __shfl_up(v, off, 64);
        if (lane >= off) v += x;
    }
    return v;
}

// ---------- init: concat -> bf16 embA; also zero flag arrays ----------
__global__ void ALGN_init_emb(const float4* __restrict__ ue, const float4* __restrict__ ie,
                              uint4* __restrict__ emb, int* __restrict__ flags,
                              int nFlags, int nUser4, int n4) {
    int t = blockIdx.x * blockDim.x + threadIdx.x;
    if (t < nFlags) flags[t] = 0;
    if (t >= n4) return;
    float4 v = (t < nUser4) ? ue[t] : ie[t - nUser4];
    uint4 o;
    o.x = pack2(v.x, v.y);
    o.y = pack2(v.z, v.w);
    // each thread handles 4 f32 = 2 words; write as two threads' worth?
    // simpler: process 8 f32 per thread via two float4 loads
    (void)o;
    // NOTE: replaced below -- see ALGN_init_emb8
}

// 8 f32 -> one uint4 (8 bf16) per thread
__global__ void ALGN_init_emb8(const float4* __restrict__ ue, const float4* __restrict__ ie,
                               uint4* __restrict__ emb, int* __restrict__ flags,
                               int nFlags, int nUser8, int n8) {
    int t = blockIdx.x * blockDim.x + threadIdx.x;
    if (t < nFlags) flags[t] = 0;
    if (t >= n8) return;
    float4 a, b;
    if (t < nUser8) { a = ue[2 * t]; b = ue[2 * t + 1]; }
    else           { a = ie[2 * (t - nUser8)]; b = ie[2 * (t - nUser8) + 1]; }
    uint4 o;
    o.x = pack2(a.x, a.y);
    o.y = pack2(a.z, a.w);
    o.z = pack2(b.x, b.y);
    o.w = pack2(b.z, b.w);
    emb[t] = o;
}

// ---------- partition pass 1: per-(block,bucket) edge counts ----------
__global__ void ALGN_p1(const int* __restrict__ rows, int* __restrict__ blockHist,
                        int nE, int seg, int nBuckets) {
    __shared__ int h[NBMAX];
    int blk = blockIdx.x;
    for (int i = threadIdx.x; i < nBuckets; i += blockDim.x) h[i] = 0;
    __syncthreads();
    int beg = blk * seg, end = min(beg + seg, nE);
    for (int e = beg + threadIdx.x; e < end; e += blockDim.x)
        atomicAdd(&h[rows[e] >> 9], 1);
    __syncthreads();
    for (int u = threadIdx.x; u < nBuckets; u += blockDim.x)
        blockHist[u * BP + blk] = h[u];          // bucket-major
}

// ---------- scanA: per bucket, exclusive scan across BP blocks ----------
// blockDim = BP = 1024 (16 waves); wave-shfl scan, 2 barriers.
__global__ void ALGN_scanA(int* __restrict__ blockHist, int* __restrict__ bucketTotal) {
    __shared__ int wsum[16];
    int b = blockIdx.x, t = threadIdx.x;
    int wid = t >> 6;
    int v = blockHist[b * BP + t];
    int isc = wave_iscan(v);
    if ((t & 63) == 63) wsum[wid] = isc;
    __syncthreads();
    if (t < 64) {
        int s = (t < 16) ? wsum[t] : 0;
        s = wave_iscan(s);
        if (t < 16) wsum[t] = s;
    }
    __syncthreads();
    int incl = isc + ((wid > 0) ? wsum[wid - 1] : 0);
    blockHist[b * BP + t] = incl - v;            // exclusive over blocks
    if (t == BP - 1) bucketTotal[b] = incl;
}

// ---------- scanB: exclusive scan of bucket totals -> bases ----------
// blockDim = 512 (8 waves).
__global__ void ALGN_scanB(const int* __restrict__ bucketTotal, int* __restrict__ bucketBase,
                           int nBuckets) {
    __shared__ int wsum[8];
    int t = threadIdx.x;
    int wid = t >> 6;
    int v = (t < nBuckets) ? bucketTotal[t] : 0;
    int isc = wave_iscan(v);
    if ((t & 63) == 63) wsum[wid] = isc;
    __syncthreads();
    if (t < 64) {
        int s = (t < 8) ? wsum[t] : 0;
        s = wave_iscan(s);
        if (t < 8) wsum[t] = s;
    }
    __syncthreads();
    int incl = isc + ((wid > 0) ? wsum[wid - 1] : 0);
    if (t < nBuckets) bucketBase[t] = incl - v;
    if (t == nBuckets - 1) bucketBase[nBuckets] = incl;
}

// ---------- partition pass 2: scatter packed records, LDS cursors ----------
// record: x = (localRow<<18) | col  (localRow<512, col<2^18), y = val bits
__global__ void ALGN_p2(const int* __restrict__ rows, const int* __restrict__ cols,
                        const float* __restrict__ vals,
                        const int* __restrict__ blockHist, const int* __restrict__ bucketBase,
                        int2* __restrict__ part, int nE, int seg, int nBuckets) {
    __shared__ int cur[NBMAX];
    int blk = blockIdx.x;
    for (int u = threadIdx.x; u < nBuckets; u += blockDim.x)
        cur[u] = bucketBase[u] + blockHist[u * BP + blk];
    __syncthreads();
    int beg = blk * seg, end = min(beg + seg, nE);
    for (int e = beg + threadIdx.x; e < end; e += blockDim.x) {
        int r = rows[e];
        int u = r >> 9;
        int pos = atomicAdd(&cur[u], 1);         // exact range by construction
        int lr = r & 511;
        part[pos] = make_int2((lr << 18) | cols[e], __float_as_int(vals[e]));
    }
}

// ---------- per-bucket counting sort -> rowPtr + row-sorted pairs ----------
// blockDim = 1024; BSZ=512 local rows; wave-shfl scan.
__global__ void ALGN_bsort(const int2* __restrict__ part, const int* __restrict__ bucketBase,
                           int2* __restrict__ pairs, int* __restrict__ rowPtr,
                           int nNodes, int nBuckets, int nE) {
    __shared__ int st[BSZ];
    __shared__ int wsum[8];
    int b = blockIdx.x, t = threadIdx.x;
    int base = bucketBase[b], lim = bucketBase[b + 1];
    if (t < BSZ) st[t] = 0;
    __syncthreads();
    for (int j = base + t; j < lim; j += blockDim.x)
        atomicAdd(&st[part[j].x >> 18], 1);
    __syncthreads();
    int wid = t >> 6;
    int v = (t < BSZ) ? st[t] : 0;
    int isc = wave_iscan(v);
    if ((t & 63) == 63 && wid < 8) wsum[wid] = isc;
    __syncthreads();
    if (t < 64) {
        int s = (t < 8) ? wsum[t] : 0;
        s = wave_iscan(s);
        if (t < 8) wsum[t] = s;
    }
    __syncthreads();
    int excl = isc - v + ((wid > 0 && wid < 8) ? wsum[wid - 1] : 0);
    __syncthreads();
    if (t < BSZ) st[t] = excl;                   // exclusive starts / cursors
    int row = b * BSZ + t;
    if (t < BSZ && row < nNodes) rowPtr[row] = base + excl;
    if (b == nBuckets - 1 && t == 0) rowPtr[nNodes] = nE;
    __syncthreads();
    for (int j = base + t; j < lim; j += blockDim.x) {
        int2 p = part[j];
        int lr = p.x >> 18;
        int pos = base + atomicAdd(&st[lr], 1);
        pairs[pos] = make_int2(p.x & 0x3FFFF, p.y);
    }
}

// ---------- demand-set flags: 16 lanes per batch row ----------
__global__ void ALGN_mark2(const int* __restrict__ rowPtr, const int2* __restrict__ pairs,
                           const int* __restrict__ users, const int* __restrict__ items,
                           int* __restrict__ flag2, int* __restrict__ flagB,
                           int batch, int nUser) {
    int tid = blockIdx.x * blockDim.x + threadIdx.x;
    int idx = tid >> 4;
    int ln  = tid & 15;
    if (idx >= 2 * batch) return;
    int row = (idx < batch) ? users[idx] : (nUser + items[idx - batch]);
    if (ln == 0) { flagB[row] = 1; flag2[row] = 1; }
    int beg = rowPtr[row], end = rowPtr[row + 1];
    for (int j = beg + ln; j < end; j += 16) flag2[pairs[j].x] = 1;
}

// ---------- SpMM row body: 8 lanes/row, uint4 = 8 bf16/lane, unroll x4 ----
__device__ __forceinline__ void acc8(float& s0, float& s1, float& s2, float& s3,
                                     float& s4, float& s5, float& s6, float& s7,
                                     float v, uint4 x) {
    s0 += v * bf2f_lo(x.x); s1 += v * bf2f_hi(x.x);
    s2 += v * bf2f_lo(x.y); s3 += v * bf2f_hi(x.y);
    s4 += v * bf2f_lo(x.z); s5 += v * bf2f_hi(x.z);
    s6 += v * bf2f_lo(x.w); s7 += v * bf2f_hi(x.w);
}

__device__ __forceinline__ void spmm_row(const uint4* __restrict__ cur,
                                         uint4* __restrict__ next,
                                         const int* __restrict__ rowPtr,
                                         const int2* __restrict__ pairs,
                                         int row, int fl) {
    int beg = rowPtr[row];
    int end = rowPtr[row + 1];
    float s0 = 0.f, s1 = 0.f, s2 = 0.f, s3 = 0.f;
    float s4 = 0.f, s5 = 0.f, s6 = 0.f, s7 = 0.f;
    int j = beg;
    for (; j + 4 <= end; j += 4) {
        int2 e0 = pairs[j + 0];
        int2 e1 = pairs[j + 1];
        int2 e2 = pairs[j + 2];
        int2 e3 = pairs[j + 3];
        uint4 x0 = cur[(size_t)e0.x * 8 + fl];
        uint4 x1 = cur[(size_t)e1.x * 8 + fl];
        uint4 x2 = cur[(size_t)e2.x * 8 + fl];
        uint4 x3 = cur[(size_t)e3.x * 8 + fl];
        acc8(s0, s1, s2, s3, s4, s5, s6, s7, __int_as_float(e0.y), x0);
        acc8(s0, s1, s2, s3, s4, s5, s6, s7, __int_as_float(e1.y), x1);
        acc8(s0, s1, s2, s3, s4, s5, s6, s7, __int_as_float(e2.y), x2);
        acc8(s0, s1, s2, s3, s4, s5, s6, s7, __int_as_float(e3.y), x3);
    }
    for (; j < end; ++j) {
        int2 e = pairs[j];
        uint4 x = cur[(size_t)e.x * 8 + fl];
        acc8(s0, s1, s2, s3, s4, s5, s6, s7, __int_as_float(e.y), x);
    }
    uint4 o;
    o.x = pack2(s0, s1);
    o.y = pack2(s2, s3);
    o.z = pack2(s4, s5);
    o.w = pack2(s6, s7);
    next[(size_t)row * 8 + fl] = o;
}

__global__ void ALGN_spmm_csr(const uint4* __restrict__ cur, uint4* __restrict__ next,
                              const int* __restrict__ rowPtr, const int2* __restrict__ pairs,
                              int nNodes) {
    int tid = blockIdx.x * blockDim.x + threadIdx.x;
    int row = tid >> 3;
    int fl  = tid & 7;
    if (row >= nNodes) return;
    spmm_row(cur, next, rowPtr, pairs, row, fl);
}

__global__ void ALGN_spmm_flag(const uint4* __restrict__ cur, uint4* __restrict__ next,
                               const int* __restrict__ rowPtr, const int2* __restrict__ pairs,
                               const int* __restrict__ flag, int nNodes) {
    int tid = blockIdx.x * blockDim.x + threadIdx.x;
    int row = tid >> 3;
    int fl  = tid & 7;
    if (row >= nNodes) return;
    if (!flag[row]) return;
    spmm_row(cur, next, rowPtr, pairs, row, fl);
}

// ---------- batch gather: layer-0 assigns (no memset), later layers add ---
__global__ void ALGN_gather_set(const unsigned short* __restrict__ emb,
                                const int* __restrict__ users, const int* __restrict__ items,
                                float* __restrict__ U, float* __restrict__ I,
                                int batch, int nUser) {
    int t = blockIdx.x * blockDim.x + threadIdx.x;
    if (t >= batch * EMB) return;
    int b = t >> 6, c = t & 63;
    U[t] = bf2f(emb[users[b] * EMB + c]) * 0.25f;
    I[t] = bf2f(emb[(nUser + items[b]) * EMB + c]) * 0.25f;
}

__global__ void ALGN_gather_add(const unsigned short* __restrict__ emb,
                                const int* __restrict__ users, const int* __restrict__ items,
                                float* __restrict__ U, float* __restrict__ I,
                                int batch, int nUser) {
    int t = blockIdx.x * blockDim.x + threadIdx.x;
    if (t >= batch * EMB) return;
    int b = t >> 6, c = t & 63;
    U[t] += bf2f(emb[users[b] * EMB + c]) * 0.25f;
    I[t] += bf2f(emb[(nUser + items[b]) * EMB + c]) * 0.25f;
}

// ---------- sigmoid(U @ I^T): 32x32 tile, 256 threads, 2x2 out/thread ----
__global__ void ALGN_gemm_sigmoid(const float* __restrict__ U, const float* __restrict__ I,
                                  float* __restrict__ out, int B) {
    __shared__ float su[32][EMB + 1];
    __shared__ float si[32][EMB + 1];
    int tx = threadIdx.x, ty = threadIdx.y;     // 16x16
    int row0 = blockIdx.y * 32, col0 = blockIdx.x * 32;
    int tid = ty * 16 + tx;
    for (int k = tid; k < 32 * EMB; k += 256) {
        int r = k >> 6, c = k & 63;
        su[r][c] = U[(row0 + r) * EMB + c];
        si[r][c] = I[(col0 + r) * EMB + c];
    }
    __syncthreads();
    float s00 = 0.f, s01 = 0.f, s10 = 0.f, s11 = 0.f;
#pragma unroll
    for (int k = 0; k < EMB; ++k) {
        float a0 = su[2 * ty][k],     a1 = su[2 * ty + 1][k];
        float b0 = si[2 * tx][k],     b1 = si[2 * tx + 1][k];
        s00 += a0 * b0; s01 += a0 * b1;
        s10 += a1 * b0; s11 += a1 * b1;
    }
    int r0 = row0 + 2 * ty, c0 = col0 + 2 * tx;
    out[(size_t)r0 * B + c0]           = 1.f / (1.f + __expf(-s00));
    out[(size_t)r0 * B + c0 + 1]       = 1.f / (1.f + __expf(-s01));
    out[(size_t)(r0 + 1) * B + c0]     = 1.f / (1.f + __expf(-s10));
    out[(size_t)(r0 + 1) * B + c0 + 1] = 1.f / (1.f + __expf(-s11));
}

extern "C" void kernel_launch(void* const* d_in, const int* in_sizes, int n_in,
                              void* d_out, int out_size, void* d_ws, size_t ws_size,
                              hipStream_t stream) {
    const float* user_emb = (const float*)d_in[0];
    const float* item_emb = (const float*)d_in[1];
    const float* adj_vals = (const float*)d_in[2];
    const int*   adj_rows = (const int*)d_in[3];
    const int*   adj_cols = (const int*)d_in[4];
    const int*   users    = (const int*)d_in[5];
    const int*   items    = (const int*)d_in[6];
    float* out = (float*)d_out;

    const int nUserF = in_sizes[0];
    const int nItemF = in_sizes[1];
    const int nEdges = in_sizes[2];
    const int batch  = in_sizes[5];
    const int nUser  = nUserF / EMB;
    const int totalF = nUserF + nItemF;
    const int nNodes = totalF / EMB;
    const int n8     = totalF / 8;
    const int nBuckets = (nNodes + BSZ - 1) / BSZ;   // 293
    const int seg    = (nEdges + BP - 1) / BP;       // 1954

    unsigned short* embA = (unsigned short*)d_ws;
    unsigned short* embB = embA + totalF;
    float* Ub = (float*)(embB + totalF);
    float* Ib = Ub + (size_t)batch * EMB;
    int2*  pairs = (int2*)(Ib + (size_t)batch * EMB);
    int2*  part  = pairs + nEdges;
    int*   rowPtr = (int*)(part + nEdges);
    int*   blockHist   = rowPtr + (nNodes + 1);
    int*   bucketTotal = blockHist + NBMAX * BP;
    int*   bucketBase  = bucketTotal + NBMAX;
    int*   flag2 = bucketBase + (NBMAX + 1);
    int*   flagB = flag2 + nNodes;

    // init (also zeroes flag2+flagB, contiguous 2*nNodes ints)
    ALGN_init_emb8<<<(n8 + 255) / 256, 256, 0, stream>>>(
        (const float4*)user_emb, (const float4*)item_emb, (uint4*)embA,
        flag2, 2 * nNodes, nUserF / 8, n8);

    // ---- deterministic CSR build ----
    ALGN_p1<<<BP, 256, 0, stream>>>(adj_rows, blockHist, nEdges, seg, nBuckets);
    ALGN_scanA<<<nBuckets, BP, 0, stream>>>(blockHist, bucketTotal);
    ALGN_scanB<<<1, 512, 0, stream>>>(bucketTotal, bucketBase, nBuckets);
    ALGN_p2<<<BP, 256, 0, stream>>>(adj_rows, adj_cols, adj_vals,
                                    blockHist, bucketBase, part, nEdges, seg, nBuckets);
    ALGN_bsort<<<nBuckets, 1024, 0, stream>>>(part, bucketBase, pairs, rowPtr,
                                              nNodes, nBuckets, nEdges);

    // ---- demand-set flags ----
    ALGN_mark2<<<(2 * batch * 16 + 255) / 256, 256, 0, stream>>>(
        rowPtr, pairs, users, items, flag2, flagB, batch, nUser);

    // ---- layer 0 contribution (assign: no memset needed) ----
    ALGN_gather_set<<<(batch * EMB + 255) / 256, 256, 0, stream>>>(
        embA, users, items, Ub, Ib, batch, nUser);

    const int fullBlocks = (nNodes * 8 + 255) / 256;

    // ---- layer 1: full ----
    ALGN_spmm_csr<<<fullBlocks, 256, 0, stream>>>(
        (const uint4*)embA, (uint4*)embB, rowPtr, pairs, nNodes);
    ALGN_gather_add<<<(batch * EMB + 255) / 256, 256, 0, stream>>>(
        embB, users, items, Ub, Ib, batch, nUser);

    // ---- layer 2: S2 rows only ----
    ALGN_spmm_flag<<<fullBlocks, 256, 0, stream>>>(
        (const uint4*)embB, (uint4*)embA, rowPtr, pairs, flag2, nNodes);
    ALGN_gather_add<<<(batch * EMB + 255) / 256, 256, 0, stream>>>(
        embA, users, items, Ub, Ib, batch, nUser);

    // ---- layer 3: batch rows only ----
    ALGN_spmm_flag<<<fullBlocks, 256, 0, stream>>>(
        (const uint4*)embA, (uint4*)embB, rowPtr, pairs, flagB, nNodes);
    ALGN_gather_add<<<(batch * EMB + 255) / 256, 256, 0, stream>>>(
        embB, users, items, Ub, Ib, batch, nUser);

    dim3 gg(batch / 32, batch / 32);
    dim3 gb(16, 16);
    ALGN_gemm_sigmoid<<<gg, gb, 0, stream>>>(Ub, Ib, out, batch);
}

// Round 12
// 280.222 us; speedup vs baseline: 18.7934x; 1.0183x over previous
//
#include <hip/hip_runtime.h>
#include <hip/hip_bf16.h>

// LightGCN on MI355X. R12: more p2 parallelism + dispatch fusion.
// R11 post-mortem: p2 now the top kernel (43 us, occupancy 29%, VALU 1.5%,
// write path 1.2 TB/s -- latency-bound, not BW-bound). spmm_csr fell below
// 43 us after the 8-lane/uint4 MLP change.
// R12: (1) BP 1024->2048 (p2 occupancy ~56%; scanA does 2 elems/thread);
//      (2) fuse (init_emb8 | p1) and (mark2 | gather_set) -- independent
//          pairs, block-range split; 13 -> 11 dispatches.
// Diagnostic: if p2 time is flat while WRITE_SIZE rises 52->~85 MB, p2 is
// write-amplification-bound -> R13 pivots to LDS-staged flush.
//
// d_ws (4B units): embA bf16[totalF] | embB bf16[totalF] | Ub[B*64] |
//   Ib[B*64] | pairs int2[E] | part int2[E] | rowPtr[N+1] |
//   blockHist[NBMAX*BP] | bucketTotal[NBMAX] | bucketBase[NBMAX+1] |
//   flag2[N] | flagB[N]   (~79 MB; 95 MB proven available)

#define EMB 64
#define BSZ 512         // rows per bucket (pow2: lr = r&511, u = r>>9)
#define NBMAX 512       // max buckets (actual: ceil(150000/512)=293)
#define BP 2048         // partition blocks (edge segments)

__device__ __forceinline__ float bf2f_lo(unsigned int u) {
    return __int_as_float((int)(u << 16));
}
__device__ __forceinline__ float bf2f_hi(unsigned int u) {
    return __int_as_float((int)(u & 0xFFFF0000u));
}
__device__ __forceinline__ float bf2f(unsigned short u) {
    return __int_as_float(((int)u) << 16);
}
__device__ __forceinline__ unsigned short f2bf(float f) {
    union { float f; unsigned int i; } v;
    v.f = f;
    unsigned int lsb = (v.i >> 16) & 1;
    v.i += 0x7fffu + lsb;          // round-to-nearest-even
    return (unsigned short)(v.i >> 16);
}
__device__ __forceinline__ unsigned int pack2(float a, float b) {
    return (unsigned int)f2bf(a) | ((unsigned int)f2bf(b) << 16);
}

// inclusive scan across a 64-lane wave (no barriers)
__device__ __forceinline__ int wave_iscan(int v) {
    int lane = threadIdx.x & 63;
#pragma unroll
    for (int off = 1; off < 64; off <<= 1) {
        int x = __shfl_up(v, off, 64);
        if (lane >= off) v += x;
    }
    return v;
}

// ---------- fused: init (concat->bf16, zero flags) | p1 (bucket hist) -----
// blocks [0, initBlocks): init; [initBlocks, initBlocks+BP): p1.
__global__ void ALGN_init_p1(const float4* __restrict__ ue, const float4* __restrict__ ie,
                             uint4* __restrict__ emb, int* __restrict__ flags, int nFlags,
                             int nUser8, int n8, int initBlocks,
                             const int* __restrict__ rows, int* __restrict__ blockHist,
                             int nE, int seg, int nBuckets) {
    __shared__ int h[NBMAX];
    if (blockIdx.x < initBlocks) {
        int t = blockIdx.x * blockDim.x + threadIdx.x;
        if (t < nFlags) flags[t] = 0;
        if (t >= n8) return;
        float4 a, b;
        if (t < nUser8) { a = ue[2 * t]; b = ue[2 * t + 1]; }
        else           { a = ie[2 * (t - nUser8)]; b = ie[2 * (t - nUser8) + 1]; }
        uint4 o;
        o.x = pack2(a.x, a.y);
        o.y = pack2(a.z, a.w);
        o.z = pack2(b.x, b.y);
        o.w = pack2(b.z, b.w);
        emb[t] = o;
    } else {
        int blk = blockIdx.x - initBlocks;
        for (int i = threadIdx.x; i < nBuckets; i += blockDim.x) h[i] = 0;
        __syncthreads();
        int beg = blk * seg, end = min(beg + seg, nE);
        for (int e = beg + threadIdx.x; e < end; e += blockDim.x)
            atomicAdd(&h[rows[e] >> 9], 1);
        __syncthreads();
        for (int u = threadIdx.x; u < nBuckets; u += blockDim.x)
            blockHist[u * BP + blk] = h[u];      // bucket-major
    }
}

// ---------- scanA: per bucket, exclusive scan across BP=2048 blocks -------
// blockDim = 1024, 2 elements/thread; wave-shfl scan.
__global__ void ALGN_scanA(int* __restrict__ blockHist, int* __restrict__ bucketTotal) {
    __shared__ int wsum[16];
    int b = blockIdx.x, t = threadIdx.x;
    int wid = t >> 6;
    int v0 = blockHist[b * BP + 2 * t];
    int v1 = blockHist[b * BP + 2 * t + 1];
    int s = v0 + v1;
    int isc = wave_iscan(s);
    if ((t & 63) == 63) wsum[wid] = isc;
    __syncthreads();
    if (t < 64) {
        int x = (t < 16) ? wsum[t] : 0;
        x = wave_iscan(x);
        if (t < 16) wsum[t] = x;
    }
    __syncthreads();
    int incl = isc + ((wid > 0) ? wsum[wid - 1] : 0);
    int excl = incl - s;
    blockHist[b * BP + 2 * t]     = excl;        // exclusive over blocks
    blockHist[b * BP + 2 * t + 1] = excl + v0;
    if (t == 1023) bucketTotal[b] = incl;
}

// ---------- scanB: exclusive scan of bucket totals -> bases ----------
// blockDim = 512 (8 waves).
__global__ void ALGN_scanB(const int* __restrict__ bucketTotal, int* __restrict__ bucketBase,
                           int nBuckets) {
    __shared__ int wsum[8];
    int t = threadIdx.x;
    int wid = t >> 6;
    int v = (t < nBuckets) ? bucketTotal[t] : 0;
    int isc = wave_iscan(v);
    if ((t & 63) == 63) wsum[wid] = isc;
    __syncthreads();
    if (t < 64) {
        int s = (t < 8) ? wsum[t] : 0;
        s = wave_iscan(s);
        if (t < 8) wsum[t] = s;
    }
    __syncthreads();
    int incl = isc + ((wid > 0) ? wsum[wid - 1] : 0);
    if (t < nBuckets) bucketBase[t] = incl - v;
    if (t == nBuckets - 1) bucketBase[nBuckets] = incl;
}

// ---------- partition pass 2: scatter packed records, LDS cursors ----------
// record: x = (localRow<<18) | col  (localRow<512, col<2^18), y = val bits
__global__ void ALGN_p2(const int* __restrict__ rows, const int* __restrict__ cols,
                        const float* __restrict__ vals,
                        const int* __restrict__ blockHist, const int* __restrict__ bucketBase,
                        int2* __restrict__ part, int nE, int seg, int nBuckets) {
    __shared__ int cur[NBMAX];
    int blk = blockIdx.x;
    for (int u = threadIdx.x; u < nBuckets; u += blockDim.x)
        cur[u] = bucketBase[u] + blockHist[u * BP + blk];
    __syncthreads();
    int beg = blk * seg, end = min(beg + seg, nE);
    for (int e = beg + threadIdx.x; e < end; e += blockDim.x) {
        int r = rows[e];
        int u = r >> 9;
        int pos = atomicAdd(&cur[u], 1);         // exact range by construction
        int lr = r & 511;
        part[pos] = make_int2((lr << 18) | cols[e], __float_as_int(vals[e]));
    }
}

// ---------- per-bucket counting sort -> rowPtr + row-sorted pairs ----------
// blockDim = 1024; BSZ=512 local rows; wave-shfl scan.
__global__ void ALGN_bsort(const int2* __restrict__ part, const int* __restrict__ bucketBase,
                           int2* __restrict__ pairs, int* __restrict__ rowPtr,
                           int nNodes, int nBuckets, int nE) {
    __shared__ int st[BSZ];
    __shared__ int wsum[8];
    int b = blockIdx.x, t = threadIdx.x;
    int base = bucketBase[b], lim = bucketBase[b + 1];
    if (t < BSZ) st[t] = 0;
    __syncthreads();
    for (int j = base + t; j < lim; j += blockDim.x)
        atomicAdd(&st[part[j].x >> 18], 1);
    __syncthreads();
    int wid = t >> 6;
    int v = (t < BSZ) ? st[t] : 0;
    int isc = wave_iscan(v);
    if ((t & 63) == 63 && wid < 8) wsum[wid] = isc;
    __syncthreads();
    if (t < 64) {
        int s = (t < 8) ? wsum[t] : 0;
        s = wave_iscan(s);
        if (t < 8) wsum[t] = s;
    }
    __syncthreads();
    int excl = isc - v + ((wid > 0 && wid < 8) ? wsum[wid - 1] : 0);
    __syncthreads();
    if (t < BSZ) st[t] = excl;                   // exclusive starts / cursors
    int row = b * BSZ + t;
    if (t < BSZ && row < nNodes) rowPtr[row] = base + excl;
    if (b == nBuckets - 1 && t == 0) rowPtr[nNodes] = nE;
    __syncthreads();
    for (int j = base + t; j < lim; j += blockDim.x) {
        int2 p = part[j];
        int lr = p.x >> 18;
        int pos = base + atomicAdd(&st[lr], 1);
        pairs[pos] = make_int2(p.x & 0x3FFFF, p.y);
    }
}

// ---------- fused: mark2 (demand flags) | gather_set (layer 0) ----------
// blocks [0, markBlocks): mark2 (16 lanes/batch row);
// [markBlocks, markBlocks+gsBlocks): gather_set.
__global__ void ALGN_mark_gather(const int* __restrict__ rowPtr, const int2* __restrict__ pairs,
                                 const int* __restrict__ users, const int* __restrict__ items,
                                 int* __restrict__ flag2, int* __restrict__ flagB,
                                 int batch, int nUser, int markBlocks,
                                 const unsigned short* __restrict__ emb,
                                 float* __restrict__ U, float* __restrict__ I) {
    if (blockIdx.x < markBlocks) {
        int tid = blockIdx.x * blockDim.x + threadIdx.x;
        int idx = tid >> 4;
        int ln  = tid & 15;
        if (idx >= 2 * batch) return;
        int row = (idx < batch) ? users[idx] : (nUser + items[idx - batch]);
        if (ln == 0) { flagB[row] = 1; flag2[row] = 1; }
        int beg = rowPtr[row], end = rowPtr[row + 1];
        for (int j = beg + ln; j < end; j += 16) flag2[pairs[j].x] = 1;
    } else {
        int t = (blockIdx.x - markBlocks) * blockDim.x + threadIdx.x;
        if (t >= batch * EMB) return;
        int b = t >> 6, c = t & 63;
        U[t] = bf2f(emb[users[b] * EMB + c]) * 0.25f;
        I[t] = bf2f(emb[(nUser + items[b]) * EMB + c]) * 0.25f;
    }
}

// ---------- SpMM row body: 8 lanes/row, uint4 = 8 bf16/lane, unroll x4 ----
__device__ __forceinline__ void acc8(float& s0, float& s1, float& s2, float& s3,
                                     float& s4, float& s5, float& s6, float& s7,
                                     float v, uint4 x) {
    s0 += v * bf2f_lo(x.x); s1 += v * bf2f_hi(x.x);
    s2 += v * bf2f_lo(x.y); s3 += v * bf2f_hi(x.y);
    s4 += v * bf2f_lo(x.z); s5 += v * bf2f_hi(x.z);
    s6 += v * bf2f_lo(x.w); s7 += v * bf2f_hi(x.w);
}

__device__ __forceinline__ void spmm_row(const uint4* __restrict__ cur,
                                         uint4* __restrict__ next,
                                         const int* __restrict__ rowPtr,
                                         const int2* __restrict__ pairs,
                                         int row, int fl) {
    int beg = rowPtr[row];
    int end = rowPtr[row + 1];
    float s0 = 0.f, s1 = 0.f, s2 = 0.f, s3 = 0.f;
    float s4 = 0.f, s5 = 0.f, s6 = 0.f, s7 = 0.f;
    int j = beg;
    for (; j + 4 <= end; j += 4) {
        int2 e0 = pairs[j + 0];
        int2 e1 = pairs[j + 1];
        int2 e2 = pairs[j + 2];
        int2 e3 = pairs[j + 3];
        uint4 x0 = cur[(size_t)e0.x * 8 + fl];
        uint4 x1 = cur[(size_t)e1.x * 8 + fl];
        uint4 x2 = cur[(size_t)e2.x * 8 + fl];
        uint4 x3 = cur[(size_t)e3.x * 8 + fl];
        acc8(s0, s1, s2, s3, s4, s5, s6, s7, __int_as_float(e0.y), x0);
        acc8(s0, s1, s2, s3, s4, s5, s6, s7, __int_as_float(e1.y), x1);
        acc8(s0, s1, s2, s3, s4, s5, s6, s7, __int_as_float(e2.y), x2);
        acc8(s0, s1, s2, s3, s4, s5, s6, s7, __int_as_float(e3.y), x3);
    }
    for (; j < end; ++j) {
        int2 e = pairs[j];
        uint4 x = cur[(size_t)e.x * 8 + fl];
        acc8(s0, s1, s2, s3, s4, s5, s6, s7, __int_as_float(e.y), x);
    }
    uint4 o;
    o.x = pack2(s0, s1);
    o.y = pack2(s2, s3);
    o.z = pack2(s4, s5);
    o.w = pack2(s6, s7);
    next[(size_t)row * 8 + fl] = o;
}

__global__ void ALGN_spmm_csr(const uint4* __restrict__ cur, uint4* __restrict__ next,
                              const int* __restrict__ rowPtr, const int2* __restrict__ pairs,
                              int nNodes) {
    int tid = blockIdx.x * blockDim.x + threadIdx.x;
    int row = tid >> 3;
    int fl  = tid & 7;
    if (row >= nNodes) return;
    spmm_row(cur, next, rowPtr, pairs, row, fl);
}

__global__ void ALGN_spmm_flag(const uint4* __restrict__ cur, uint4* __restrict__ next,
                               const int* __restrict__ rowPtr, const int2* __restrict__ pairs,
                               const int* __restrict__ flag, int nNodes) {
    int tid = blockIdx.x * blockDim.x + threadIdx.x;
    int row = tid >> 3;
    int fl  = tid & 7;
    if (row >= nNodes) return;
    if (!flag[row]) return;
    spmm_row(cur, next, rowPtr, pairs, row, fl);
}

// ---------- batch gather-accumulate (layer mean 0.25 folded per side) -----
__global__ void ALGN_gather_add(const unsigned short* __restrict__ emb,
                                const int* __restrict__ users, const int* __restrict__ items,
                                float* __restrict__ U, float* __restrict__ I,
                                int batch, int nUser) {
    int t = blockIdx.x * blockDim.x + threadIdx.x;
    if (t >= batch * EMB) return;
    int b = t >> 6, c = t & 63;
    U[t] += bf2f(emb[users[b] * EMB + c]) * 0.25f;
    I[t] += bf2f(emb[(nUser + items[b]) * EMB + c]) * 0.25f;
}

// ---------- sigmoid(U @ I^T): 32x32 tile, 256 threads, 2x2 out/thread ----
__global__ void ALGN_gemm_sigmoid(const float* __restrict__ U, const float* __restrict__ I,
                                  float* __restrict__ out, int B) {
    __shared__ float su[32][EMB + 1];
    __shared__ float si[32][EMB + 1];
    int tx = threadIdx.x, ty = threadIdx.y;     // 16x16
    int row0 = blockIdx.y * 32, col0 = blockIdx.x * 32;
    int tid = ty * 16 + tx;
    for (int k = tid; k < 32 * EMB; k += 256) {
        int r = k >> 6, c = k & 63;
        su[r][c] = U[(row0 + r) * EMB + c];
        si[r][c] = I[(col0 + r) * EMB + c];
    }
    __syncthreads();
    float s00 = 0.f, s01 = 0.f, s10 = 0.f, s11 = 0.f;
#pragma unroll
    for (int k = 0; k < EMB; ++k) {
        float a0 = su[2 * ty][k],     a1 = su[2 * ty + 1][k];
        float b0 = si[2 * tx][k],     b1 = si[2 * tx + 1][k];
        s00 += a0 * b0; s01 += a0 * b1;
        s10 += a1 * b0; s11 += a1 * b1;
    }
    int r0 = row0 + 2 * ty, c0 = col0 + 2 * tx;
    out[(size_t)r0 * B + c0]           = 1.f / (1.f + __expf(-s00));
    out[(size_t)r0 * B + c0 + 1]       = 1.f / (1.f + __expf(-s01));
    out[(size_t)(r0 + 1) * B + c0]     = 1.f / (1.f + __expf(-s10));
    out[(size_t)(r0 + 1) * B + c0 + 1] = 1.f / (1.f + __expf(-s11));
}

extern "C" void kernel_launch(void* const* d_in, const int* in_sizes, int n_in,
                              void* d_out, int out_size, void* d_ws, size_t ws_size,
                              hipStream_t stream) {
    const float* user_emb = (const float*)d_in[0];
    const float* item_emb = (const float*)d_in[1];
    const float* adj_vals = (const float*)d_in[2];
    const int*   adj_rows = (const int*)d_in[3];
    const int*   adj_cols = (const int*)d_in[4];
    const int*   users    = (const int*)d_in[5];
    const int*   items    = (const int*)d_in[6];
    float* out = (float*)d_out;

    const int nUserF = in_sizes[0];
    const int nItemF = in_sizes[1];
    const int nEdges = in_sizes[2];
    const int batch  = in_sizes[5];
    const int nUser  = nUserF / EMB;
    const int totalF = nUserF + nItemF;
    const int nNodes = totalF / EMB;
    const int n8     = totalF / 8;
    const int nBuckets = (nNodes + BSZ - 1) / BSZ;   // 293
    const int seg    = (nEdges + BP - 1) / BP;       // 977

    unsigned short* embA = (unsigned short*)d_ws;
    unsigned short* embB = embA + totalF;
    float* Ub = (float*)(embB + totalF);
    float* Ib = Ub + (size_t)batch * EMB;
    int2*  pairs = (int2*)(Ib + (size_t)batch * EMB);
    int2*  part  = pairs + nEdges;
    int*   rowPtr = (int*)(part + nEdges);
    int*   blockHist   = rowPtr + (nNodes + 1);
    int*   bucketTotal = blockHist + NBMAX * BP;
    int*   bucketBase  = bucketTotal + NBMAX;
    int*   flag2 = bucketBase + (NBMAX + 1);
    int*   flagB = flag2 + nNodes;

    // ---- fused init | p1 ----
    const int initBlocks = (n8 + 255) / 256;         // covers n8 and 2*nNodes flags
    ALGN_init_p1<<<initBlocks + BP, 256, 0, stream>>>(
        (const float4*)user_emb, (const float4*)item_emb, (uint4*)embA,
        flag2, 2 * nNodes, nUserF / 8, n8, initBlocks,
        adj_rows, blockHist, nEdges, seg, nBuckets);

    // ---- deterministic CSR build ----
    ALGN_scanA<<<nBuckets, 1024, 0, stream>>>(blockHist, bucketTotal);
    ALGN_scanB<<<1, 512, 0, stream>>>(bucketTotal, bucketBase, nBuckets);
    ALGN_p2<<<BP, 256, 0, stream>>>(adj_rows, adj_cols, adj_vals,
                                    blockHist, bucketBase, part, nEdges, seg, nBuckets);
    ALGN_bsort<<<nBuckets, 1024, 0, stream>>>(part, bucketBase, pairs, rowPtr,
                                              nNodes, nBuckets, nEdges);

    // ---- fused mark2 | gather_set ----
    const int markBlocks = (2 * batch * 16 + 255) / 256;
    const int gsBlocks   = (batch * EMB + 255) / 256;
    ALGN_mark_gather<<<markBlocks + gsBlocks, 256, 0, stream>>>(
        rowPtr, pairs, users, items, flag2, flagB, batch, nUser, markBlocks,
        embA, Ub, Ib);

    const int fullBlocks = (nNodes * 8 + 255) / 256;

    // ---- layer 1: full ----
    ALGN_spmm_csr<<<fullBlocks, 256, 0, stream>>>(
        (const uint4*)embA, (uint4*)embB, rowPtr, pairs, nNodes);
    ALGN_gather_add<<<(batch * EMB + 255) / 256, 256, 0, stream>>>(
        embB, users, items, Ub, Ib, batch, nUser);

    // ---- layer 2: S2 rows only ----
    ALGN_spmm_flag<<<fullBlocks, 256, 0, stream>>>(
        (const uint4*)embB, (uint4*)embA, rowPtr, pairs, flag2, nNodes);
    ALGN_gather_add<<<(batch * EMB + 255) / 256, 256, 0, stream>>>(
        embA, users, items, Ub, Ib, batch, nUser);

    // ---- layer 3: batch rows only ----
    ALGN_spmm_flag<<<fullBlocks, 256, 0, stream>>>(
        (const uint4*)embA, (uint4*)embB, rowPtr, pairs, flagB, nNodes);
    ALGN_gather_add<<<(batch * EMB + 255) / 256, 256, 0, stream>>>(
        embB, users, items, Ub, Ib, batch, nUser);

    dim3 gg(batch / 32, batch / 32);
    dim3 gb(16, 16);
    ALGN_gemm_sigmoid<<<gg, gb, 0, stream>>>(Ub, Ib, out, batch);
}